// Round 8
// baseline (632.713 us; speedup 1.0000x reference)
//
#include <hip/hip_runtime.h>
#include <hip/hip_bf16.h>

typedef __attribute__((ext_vector_type(8))) short bf16x8;
typedef __attribute__((ext_vector_type(4))) float f32x4;

#define BSH 8
#define BNODES 256  // nodes per bucket = 1 << BSH

__device__ __forceinline__ unsigned short f2bf(float f) {
    union { float f; unsigned int u; } x; x.f = f;
    unsigned int u = x.u;
    unsigned int r = (u + 0x7fffu + ((u >> 16) & 1u)) >> 16;  // RNE
    return (unsigned short)r;
}
__device__ __forceinline__ float bf_lo(unsigned int v) { return __uint_as_float(v << 16); }
__device__ __forceinline__ float bf_hi(unsigned int v) { return __uint_as_float(v & 0xffff0000u); }

__device__ __forceinline__ void gll16(const void* g, void* l) {
    __builtin_amdgcn_global_load_lds(
        (const __attribute__((address_space(1))) unsigned int*)g,
        (__attribute__((address_space(3))) unsigned int*)l, 16, 0, 0);
}

template <int N> __device__ __forceinline__ void waitvm() {
    if constexpr (N == 0) asm volatile("s_waitcnt vmcnt(0)" ::: "memory");
    else if constexpr (N == 4) asm volatile("s_waitcnt vmcnt(4)" ::: "memory");
    else if constexpr (N == 6) asm volatile("s_waitcnt vmcnt(6)" ::: "memory");
    else static_assert(N == 0, "unhandled vmcnt");
}

// ---------------- CSR build: binned, write-locality-aware ----------------

__global__ void k_zero(int* p, int n) {
    int i = blockIdx.x * 256 + threadIdx.x;
    if (i < n) p[i] = 0;
}

__global__ __launch_bounds__(256) void kA_hist(const int* __restrict__ dst, int* bhist,
                                               int E, int nbkt) {
    __shared__ int h[512];
    for (int i = threadIdx.x; i < 512; i += 256) h[i] = 0;
    __syncthreads();
    int stride = gridDim.x * 256;
    int n4 = E >> 2;
    for (int i = blockIdx.x * 256 + threadIdx.x; i < n4; i += stride) {
        int4 d = ((const int4*)dst)[i];
        atomicAdd(&h[d.x >> BSH], 1);
        atomicAdd(&h[d.y >> BSH], 1);
        atomicAdd(&h[d.z >> BSH], 1);
        atomicAdd(&h[d.w >> BSH], 1);
    }
    for (int i = (n4 << 2) + blockIdx.x * 256 + threadIdx.x; i < E; i += stride)
        atomicAdd(&h[dst[i] >> BSH], 1);
    __syncthreads();
    for (int i = threadIdx.x; i < nbkt; i += 256)
        if (h[i]) atomicAdd(&bhist[i], h[i]);
}

__global__ void kA_scan(const int* bhist, int* bbase, int* bcur, int nbkt) {
    __shared__ int s[512];
    int t = threadIdx.x;
    int v = (t < nbkt) ? bhist[t] : 0;
    s[t] = v;
    __syncthreads();
    for (int o = 1; o < 512; o <<= 1) {
        int x = (t >= o) ? s[t - o] : 0;
        __syncthreads();
        s[t] += x;
        __syncthreads();
    }
    if (t < nbkt) { bbase[t] = s[t] - v; bcur[t] = s[t] - v; }
    if (t == nbkt - 1) bbase[nbkt] = s[t];
}

#define TPE 16
__global__ __launch_bounds__(256) void kA_scatter(const int* __restrict__ src,
                                                  const int* __restrict__ dst,
                                                  int* bcur, unsigned int* pairs,
                                                  int E, int nbkt) {
    __shared__ int hist[512];
    __shared__ int base[512];
    const int tid = threadIdx.x;
    const int t0 = blockIdx.x * (256 * TPE);
    for (int i = tid; i < 512; i += 256) hist[i] = 0;
    __syncthreads();

    int es[TPE], ed[TPE], rk[TPE];
    bool valid[TPE];
    if (t0 + 256 * TPE <= E) {
        const int4* s4 = (const int4*)(src + t0 + tid * TPE);
        const int4* d4 = (const int4*)(dst + t0 + tid * TPE);
#pragma unroll
        for (int j = 0; j < TPE / 4; j++) {
            int4 a = s4[j], b = d4[j];
            es[4 * j + 0] = a.x; es[4 * j + 1] = a.y; es[4 * j + 2] = a.z; es[4 * j + 3] = a.w;
            ed[4 * j + 0] = b.x; ed[4 * j + 1] = b.y; ed[4 * j + 2] = b.z; ed[4 * j + 3] = b.w;
            valid[4 * j + 0] = valid[4 * j + 1] = valid[4 * j + 2] = valid[4 * j + 3] = true;
        }
    } else {
#pragma unroll
        for (int j = 0; j < TPE; j++) {
            int e = t0 + tid * TPE + j;
            valid[j] = (e < E);
            es[j] = valid[j] ? src[e] : 0;
            ed[j] = valid[j] ? dst[e] : 0;
        }
    }
#pragma unroll
    for (int j = 0; j < TPE; j++)
        if (valid[j]) rk[j] = atomicAdd(&hist[ed[j] >> BSH], 1);
    __syncthreads();
    for (int i = tid; i < nbkt; i += 256) {
        int c = hist[i];
        base[i] = c ? atomicAdd(&bcur[i], c) : 0;
    }
    __syncthreads();
#pragma unroll
    for (int j = 0; j < TPE; j++) {
        if (valid[j]) {
            int b = ed[j] >> BSH;
            unsigned int p = ((unsigned int)(ed[j] & (BNODES - 1)) << 24) | (unsigned int)es[j];
            pairs[base[b] + rk[j]] = p;
        }
    }
}

__global__ __launch_bounds__(512) void kB_group(const unsigned int* __restrict__ pairs,
                                                const int* __restrict__ bbase,
                                                int* csr, int* offs, int* cnt, float* dinv,
                                                int N, int nbkt) {
    int b = blockIdx.x;
    int p0 = bbase[b], p1 = bbase[b + 1];
    int node0 = b << BSH;
    int nn = min(BNODES, N - node0);
    __shared__ int lcnt[BNODES];
    __shared__ int ss[BNODES];
    __shared__ int lcur[BNODES];
    int t = threadIdx.x;
    if (t < BNODES) lcnt[t] = 0;
    __syncthreads();
    for (int i = p0 + t; i < p1; i += 512)
        atomicAdd(&lcnt[pairs[i] >> 24], 1);
    __syncthreads();
    int v = (t < BNODES) ? lcnt[t] : 0;
    if (t < BNODES) ss[t] = v;
    __syncthreads();
    for (int o = 1; o < BNODES; o <<= 1) {
        int x = (t >= o && t < BNODES) ? ss[t - o] : 0;
        __syncthreads();
        if (t < BNODES) ss[t] += x;
        __syncthreads();
    }
    if (t < nn) {
        int o = p0 + ss[t] - v;
        offs[node0 + t] = o;
        cnt[node0 + t] = v;
        dinv[node0 + t] = rsqrtf((float)(v + 1));
        lcur[t] = o;
    }
    __syncthreads();
    for (int i = p0 + t; i < p1; i += 512) {
        unsigned int p = pairs[i];
        int pos = atomicAdd(&lcur[p >> 24], 1);
        csr[pos] = (int)(p & 0xFFFFFFu);
    }
}

// W1 [1024][128] + W2 [128][128] fp32 -> transposed bf16 in one launch
__global__ void k_wt2(const float* __restrict__ W1, unsigned short* w1t,
                      const float* __restrict__ W2, unsigned short* w2t) {
    int i = blockIdx.x * 256 + threadIdx.x;
    if (i < 1024 * 128) {
        int k = i >> 7, c = i & 127;
        w1t[c * 1024 + k] = f2bf(W1[i]);
    } else {
        int j = i - 1024 * 128;
        if (j < 128 * 128) {
            int k = j >> 7, c = j & 127;
            w2t[c * 128 + k] = f2bf(W2[j]);
        }
    }
}

// ---------------- GEMM1: [M][1024]f32 @ w1t -> g bf16. DRAM-pattern-friendly. ----------------
// BM=32, BK=256. Two INDEPENDENT waves per block (16 rows each, own LDS region,
// zero barriers). Staging: 16x contiguous-1KB float4 row-spans into registers
// (issued early), cvt->bf16 ds_write after compute (T14 split). Double-buffered.
// Row pad +8 shorts => conflict-free ds_read_b128. B streamed from L2-resident w1t.

#define G1_RS 264                 // LDS row stride in shorts (256 + 8 pad)
#define G1_BUF (16 * G1_RS)       // shorts per buffer per wave

__global__ __launch_bounds__(128) void k_gemm1(const float* __restrict__ X,
                                               const unsigned short* __restrict__ Wt,
                                               const float* __restrict__ dinv,
                                               unsigned short* __restrict__ G, int M) {
    __shared__ unsigned short sA[2][2][G1_BUF];  // [wave][buf][.]
    const int tid = threadIdx.x;
    const int wv = tid >> 6, l = tid & 63, r = l & 15, kg = l >> 4;
    const int m0 = blockIdx.x * 32 + wv * 16;  // this wave's 16 rows
    const float* Xw = X + (size_t)m0 * 1024;

    f32x4 acc[8];
#pragma unroll
    for (int ct = 0; ct < 8; ct++) acc[ct] = (f32x4){0.f, 0.f, 0.f, 0.f};

    float4 rg[16];

#define G1_LOADREGS(c)                                                          \
    {                                                                           \
        _Pragma("unroll") for (int i = 0; i < 16; i++)                          \
            rg[i] = *(const float4*)(Xw + i * 1024 + (c) * 256 + l * 4);        \
    }

#define G1_CVTWRITE(b)                                                          \
    {                                                                           \
        unsigned short* dstb = &sA[wv][(b)][0];                                 \
        _Pragma("unroll") for (int i = 0; i < 16; i++) {                        \
            uint2 pk;                                                           \
            pk.x = (unsigned int)f2bf(rg[i].x) | ((unsigned int)f2bf(rg[i].y) << 16); \
            pk.y = (unsigned int)f2bf(rg[i].z) | ((unsigned int)f2bf(rg[i].w) << 16); \
            *(uint2*)&dstb[i * G1_RS + l * 4] = pk;                             \
        }                                                                       \
    }

#define G1_COMPUTE(b, c)                                                        \
    {                                                                           \
        const unsigned short* srcb = &sA[wv][(b)][0];                           \
        _Pragma("unroll") for (int s = 0; s < 8; s++) {                         \
            bf16x8 af = *(const bf16x8*)&srcb[r * G1_RS + s * 32 + kg * 8];     \
            _Pragma("unroll") for (int ct = 0; ct < 8; ct++) {                  \
                bf16x8 bf = *(const bf16x8*)&Wt[(ct * 16 + r) * 1024 + (c) * 256 + s * 32 + kg * 8]; \
                acc[ct] = __builtin_amdgcn_mfma_f32_16x16x32_bf16(af, bf, acc[ct], 0, 0, 0); \
            }                                                                   \
        }                                                                       \
    }

    G1_LOADREGS(0);
    G1_CVTWRITE(0);
    G1_LOADREGS(1);

    G1_COMPUTE(0, 0);
    G1_CVTWRITE(1);
    G1_LOADREGS(2);

    G1_COMPUTE(1, 1);
    G1_CVTWRITE(0);
    G1_LOADREGS(3);

    G1_COMPUTE(0, 2);
    G1_CVTWRITE(1);

    G1_COMPUTE(1, 3);

#undef G1_LOADREGS
#undef G1_CVTWRITE
#undef G1_COMPUTE

    // epilogue: C/D layout col = lane&15, row = 4*(lane>>4) + reg
    int rbase = m0 + kg * 4;
    float dv[4];
#pragma unroll
    for (int q = 0; q < 4; q++) dv[q] = (rbase + q < M) ? dinv[rbase + q] : 0.f;
#pragma unroll
    for (int ct = 0; ct < 8; ct++) {
#pragma unroll
        for (int q = 0; q < 4; q++) {
            int gr = rbase + q;
            if (gr < M) G[(size_t)gr * 128 + ct * 16 + r] = f2bf(acc[ct][q] * dv[q]);
        }
    }
}

// ---------------- GEMM2 (bf16, K=128): 3-buffer gll16 ring, counted vmcnt ----------------

template <int K>
__global__ __launch_bounds__(256) void k_gemm(const unsigned short* __restrict__ X,
                                              const unsigned short* __restrict__ Wt,
                                              const float* __restrict__ dinv,
                                              unsigned short* __restrict__ G, int M) {
    constexpr int ABYTES = 128 * 32 * 2;
    constexpr int BBYTES = 128 * 32 * 2;
    constexpr int NT = K / 32;
    constexpr int NBUF = 3;
    constexpr int L = 4;
    static_assert(NT >= 3, "pipeline needs >=3 tiles");
    __shared__ char smem[NBUF * (ABYTES + BBYTES)];

    const int tid = threadIdx.x;
    const int m0 = blockIdx.x * 128;
    const int w = tid >> 6, l = tid & 63, r = l & 15, kg = l >> 4;
    const int wb0 = tid & ~63;

    auto stage = [&](int buf, int k0) {
        char* ab = smem + buf * ABYTES;
#pragma unroll
        for (int i = 0; i < 2; i++) {
            int wb = i * 256 + wb0;
            int c = wb + l;
            int row = c >> 2, slot = c & 3;
            int srow = m0 + row; if (srow >= M) srow = M - 1;
            gll16(X + (size_t)srow * K + k0 + slot * 8, ab + (size_t)wb * 16);
        }
        char* bb = smem + NBUF * ABYTES + buf * BBYTES;
#pragma unroll
        for (int i = 0; i < 2; i++) {
            int wb = i * 256 + wb0;
            int c = wb + l;
            int row = c >> 2, slot = c & 3;
            gll16(Wt + (size_t)row * K + k0 + slot * 8, bb + (size_t)wb * 16);
        }
    };

    f32x4 acc[2][8];
#pragma unroll
    for (int mt = 0; mt < 2; mt++)
#pragma unroll
        for (int ct = 0; ct < 8; ct++) acc[mt][ct] = (f32x4){0.f, 0.f, 0.f, 0.f};

    auto compute = [&](int buf) {
        bf16x8 af[2], bfr[8];
        const unsigned short* ab = (const unsigned short*)(smem + buf * ABYTES);
#pragma unroll
        for (int mt = 0; mt < 2; mt++) {
            int row = w * 32 + mt * 16 + r;
            af[mt] = *(const bf16x8*)(ab + row * 32 + kg * 8);
        }
        const unsigned short* bb = (const unsigned short*)(smem + NBUF * ABYTES + buf * BBYTES);
#pragma unroll
        for (int ct = 0; ct < 8; ct++)
            bfr[ct] = *(const bf16x8*)(bb + (ct * 16 + r) * 32 + kg * 8);
#pragma unroll
        for (int mt = 0; mt < 2; mt++)
#pragma unroll
            for (int ct = 0; ct < 8; ct++)
                acc[mt][ct] = __builtin_amdgcn_mfma_f32_16x16x32_bf16(af[mt], bfr[ct], acc[mt][ct], 0, 0, 0);
    };

    stage(0, 0);
    stage(1, 32);

    int cur = 0;
    for (int t = 0; t < NT - 2; ++t) {
        int nb = cur + 2; if (nb >= NBUF) nb -= NBUF;
        waitvm<L>();
        __builtin_amdgcn_s_barrier();
        stage(nb, (t + 2) * 32);
        compute(cur);
        cur = (cur + 1 == NBUF) ? 0 : cur + 1;
    }
    waitvm<L>();
    __builtin_amdgcn_s_barrier();
    compute(cur);
    cur = (cur + 1 == NBUF) ? 0 : cur + 1;
    waitvm<0>();
    __builtin_amdgcn_s_barrier();
    compute(cur);

#pragma unroll
    for (int mt = 0; mt < 2; mt++) {
        int rbase = m0 + w * 32 + mt * 16 + kg * 4;
        float dv[4];
#pragma unroll
        for (int q = 0; q < 4; q++) dv[q] = (rbase + q < M) ? dinv[rbase + q] : 0.f;
#pragma unroll
        for (int ct = 0; ct < 8; ct++) {
#pragma unroll
            for (int q = 0; q < 4; q++) {
                int gr = rbase + q;
                if (gr < M) G[(size_t)gr * 128 + ct * 16 + r] = f2bf(acc[mt][ct][q] * dv[q]);
            }
        }
    }
}

// ---------------- GEMM3: [M][128]bf16 @ [128][9]f32 -> g3 [M][16]bf16 (padded) ----------------

__global__ __launch_bounds__(256) void k_gemm3(const unsigned short* X3, const float* W3,
                                               const float* dinv, unsigned short* G3, int M) {
    __shared__ unsigned short sx[128 * 136];
    __shared__ float sw[128 * 9];
    int tid = threadIdx.x;
    int m0 = blockIdx.x * 128;
#pragma unroll
    for (int p = 0; p < 8; p++) {
        int idx = p * 256 + tid;
        int row = idx >> 4, c8 = idx & 15;
        uint4 v = make_uint4(0u, 0u, 0u, 0u);
        if (m0 + row < M) v = *(const uint4*)(X3 + (size_t)(m0 + row) * 128 + c8 * 8);
        *(uint4*)&sx[row * 136 + c8 * 8] = v;
    }
    for (int i = tid; i < 128 * 9; i += 256) sw[i] = W3[i];
    __syncthreads();

    int r = tid >> 1, h = tid & 1;
    float acc[9];
#pragma unroll
    for (int c = 0; c < 9; c++) acc[c] = 0.f;
    for (int kk = 0; kk < 64; kk++) {
        int k = h * 64 + kk;
        float xv = __uint_as_float(((unsigned int)sx[r * 136 + k]) << 16);
#pragma unroll
        for (int c = 0; c < 9; c++) acc[c] += xv * sw[k * 9 + c];
    }
#pragma unroll
    for (int c = 0; c < 9; c++) acc[c] += __shfl_xor(acc[c], 1);
    int gr = m0 + r;
    if (h == 0 && gr < M) {
        float dv = dinv[gr];
#pragma unroll
        for (int c = 0; c < 9; c++) G3[(size_t)gr * 16 + c] = f2bf(acc[c] * dv);
#pragma unroll
        for (int c = 9; c < 16; c++) G3[(size_t)gr * 16 + c] = 0;
    }
}

// ---------------- aggregation, 128-dim: LDS-staged csr, 8-deep gather pipeline ----------------

#define A128_CAP 1024

__global__ __launch_bounds__(256) void k_agg128(const unsigned int* __restrict__ gv,
                                                const int* __restrict__ csr,
                                                const int* __restrict__ offs,
                                                const int* __restrict__ cnt,
                                                const float* __restrict__ dinv,
                                                const float* __restrict__ bias,
                                                unsigned int* xout, int N, int do_relu) {
    __shared__ int sidx[A128_CAP];
    const int tid = threadIdx.x;
    const int n0 = blockIdx.x * 4;
    const int nlast = min(n0 + 3, N - 1);
    const int base = offs[n0];
    const int tot = offs[nlast] + cnt[nlast] - base;
    const bool lds_ok = (tot <= A128_CAP);
    if (lds_ok)
        for (int i = tid; i < tot; i += 256) sidx[i] = csr[base + i];
    __syncthreads();

    const int node = n0 + (tid >> 6);
    if (node >= N) return;
    const int l = tid & 63;
    const int ne = cnt[node];
    const int st = offs[node] - base;

    unsigned int u = gv[node * 64 + l];
    float a0 = bf_lo(u), a1 = bf_hi(u);
    int e = 0;
    if (lds_ok) {
        for (; e + 8 <= ne; e += 8) {
            int s0 = sidx[st + e], s1 = sidx[st + e + 1];
            int s2 = sidx[st + e + 2], s3 = sidx[st + e + 3];
            int s4 = sidx[st + e + 4], s5 = sidx[st + e + 5];
            int s6 = sidx[st + e + 6], s7 = sidx[st + e + 7];
            unsigned int v0 = gv[s0 * 64 + l], v1 = gv[s1 * 64 + l];
            unsigned int v2 = gv[s2 * 64 + l], v3 = gv[s3 * 64 + l];
            unsigned int v4 = gv[s4 * 64 + l], v5 = gv[s5 * 64 + l];
            unsigned int v6 = gv[s6 * 64 + l], v7 = gv[s7 * 64 + l];
            a0 += bf_lo(v0); a1 += bf_hi(v0);
            a0 += bf_lo(v1); a1 += bf_hi(v1);
            a0 += bf_lo(v2); a1 += bf_hi(v2);
            a0 += bf_lo(v3); a1 += bf_hi(v3);
            a0 += bf_lo(v4); a1 += bf_hi(v4);
            a0 += bf_lo(v5); a1 += bf_hi(v5);
            a0 += bf_lo(v6); a1 += bf_hi(v6);
            a0 += bf_lo(v7); a1 += bf_hi(v7);
        }
        for (; e < ne; e++) {
            unsigned int v = gv[sidx[st + e] * 64 + l];
            a0 += bf_lo(v); a1 += bf_hi(v);
        }
    } else {
        const int gst = offs[node];
        for (; e < ne; e++) {
            unsigned int v = gv[csr[gst + e] * 64 + l];
            a0 += bf_lo(v); a1 += bf_hi(v);
        }
    }
    float dv = dinv[node];
    float o0 = fmaf(dv, a0, bias[2 * l]);
    float o1 = fmaf(dv, a1, bias[2 * l + 1]);
    if (do_relu) { o0 = fmaxf(o0, 0.f); o1 = fmaxf(o1, 0.f); }
    xout[node * 64 + l] = (unsigned int)f2bf(o0) | ((unsigned int)f2bf(o1) << 16);
}

// ---------------- aggregation, 9-dim + log_softmax: 8 lanes/node, 32 nodes/block ----------------

#define A9_CAP 3072

__global__ __launch_bounds__(256) void k_agg9(const unsigned int* __restrict__ g3v,
                                              const int* __restrict__ csr,
                                              const int* __restrict__ offs,
                                              const int* __restrict__ cnt,
                                              const float* __restrict__ dinv,
                                              const float* __restrict__ b3,
                                              float* out, int N) {
    __shared__ int sidx[A9_CAP];
    const int tid = threadIdx.x;
    const int n0 = blockIdx.x * 32;
    const int nlast = min(n0 + 31, N - 1);
    const int base = offs[n0];
    const int tot = offs[nlast] + cnt[nlast] - base;
    const bool lds_ok = (tot <= A9_CAP);
    if (lds_ok)
        for (int i = tid; i < tot; i += 256) sidx[i] = csr[base + i];
    __syncthreads();

    const int node = n0 + (tid >> 3);
    if (node >= N) return;
    const int jl = tid & 7;
    const int ne = cnt[node];

    unsigned int u = g3v[node * 8 + jl];
    float a0 = bf_lo(u), a1 = bf_hi(u);
    int e = 0;
    if (lds_ok) {
        const int st = offs[node] - base;
        for (; e + 4 <= ne; e += 4) {
            int s0 = sidx[st + e], s1 = sidx[st + e + 1];
            int s2 = sidx[st + e + 2], s3 = sidx[st + e + 3];
            unsigned int v0 = g3v[s0 * 8 + jl], v1 = g3v[s1 * 8 + jl];
            unsigned int v2 = g3v[s2 * 8 + jl], v3 = g3v[s3 * 8 + jl];
            a0 += bf_lo(v0); a1 += bf_hi(v0);
            a0 += bf_lo(v1); a1 += bf_hi(v1);
            a0 += bf_lo(v2); a1 += bf_hi(v2);
            a0 += bf_lo(v3); a1 += bf_hi(v3);
        }
        for (; e < ne; e++) {
            unsigned int v = g3v[sidx[st + e] * 8 + jl];
            a0 += bf_lo(v); a1 += bf_hi(v);
        }
    } else {
        const int gst = offs[node];
        for (; e < ne; e++) {
            unsigned int v = g3v[csr[gst + e] * 8 + jl];
            a0 += bf_lo(v); a1 += bf_hi(v);
        }
    }
    float dv = dinv[node];
    int c0 = 2 * jl, c1 = 2 * jl + 1;
    float o0 = (c0 < 9) ? fmaf(dv, a0, b3[c0]) : -INFINITY;
    float o1 = (c1 < 9) ? fmaf(dv, a1, b3[c1]) : -INFINITY;
    float m = fmaxf(o0, o1);
    for (int d = 1; d < 8; d <<= 1) m = fmaxf(m, __shfl_xor(m, d));
    float s = 0.f;
    if (c0 < 9) s += expf(o0 - m);
    if (c1 < 9) s += expf(o1 - m);
    for (int d = 1; d < 8; d <<= 1) s += __shfl_xor(s, d);
    float ls = m + logf(s);
    if (c0 < 9) out[(size_t)node * 9 + c0] = o0 - ls;
    if (c1 < 9) out[(size_t)node * 9 + c1] = o1 - ls;
}

// ---------------- launch ----------------

extern "C" void kernel_launch(void* const* d_in, const int* in_sizes, int n_in,
                              void* d_out, int out_size, void* d_ws, size_t ws_size,
                              hipStream_t stream) {
    const float* x = (const float*)d_in[0];
    const int* ei = (const int*)d_in[1];
    const float* W1 = (const float*)d_in[2];
    const float* b1 = (const float*)d_in[3];
    const float* W2 = (const float*)d_in[4];
    const float* b2 = (const float*)d_in[5];
    const float* W3 = (const float*)d_in[6];
    const float* b3 = (const float*)d_in[7];
    float* out = (float*)d_out;

    const int N = in_sizes[0] / 1024;
    const int E = in_sizes[1] / 2;
    const int* src = ei;
    const int* dst = ei + E;
    const int nbkt = (N + BNODES - 1) >> BSH;

    char* ws = (char*)d_ws;
    size_t off = 0;
    auto alloc = [&](size_t bytes) -> char* {
        char* p = ws + off;
        off += (bytes + 255) & ~(size_t)255;
        return p;
    };
    int* cnt = (int*)alloc((size_t)N * 4);
    int* offs = (int*)alloc((size_t)N * 4);
    float* dinv = (float*)alloc((size_t)N * 4);
    int* bhist = (int*)alloc(520 * 4);
    int* bbase = (int*)alloc(520 * 4);
    int* bcur = (int*)alloc(520 * 4);
    unsigned int* pairs = (unsigned int*)alloc((size_t)E * 4);
    int* csr = (int*)alloc((size_t)E * 4);
    unsigned short* w1t = (unsigned short*)alloc(128 * 1024 * 2);
    unsigned short* w2t = (unsigned short*)alloc(128 * 128 * 2);
    unsigned short* gbuf = (unsigned short*)alloc((size_t)N * 128 * 2);
    unsigned short* xbuf = (unsigned short*)alloc((size_t)N * 128 * 2);
    unsigned short* g3 = (unsigned short*)alloc((size_t)N * 16 * 2);

    const int MB1 = (N + 31) / 32;
    const int MB = (N + 127) / 128;
    const int AB = (N + 3) / 4;
    const int AB9 = (N + 31) / 32;
    const int SB = (E + 256 * TPE - 1) / (256 * TPE);
    const int WB = (1024 * 128 + 128 * 128 + 255) / 256;

    k_zero<<<3, 256, 0, stream>>>(bhist, 520);
    kA_hist<<<512, 256, 0, stream>>>(dst, bhist, E, nbkt);
    kA_scan<<<1, 512, 0, stream>>>(bhist, bbase, bcur, nbkt);
    kA_scatter<<<SB, 256, 0, stream>>>(src, dst, bcur, pairs, E, nbkt);
    kB_group<<<nbkt, 512, 0, stream>>>(pairs, bbase, csr, offs, cnt, dinv, N, nbkt);
    k_wt2<<<WB, 256, 0, stream>>>(W1, w1t, W2, w2t);

    k_gemm1<<<MB1, 128, 0, stream>>>(x, w1t, dinv, gbuf, N);
    k_agg128<<<AB, 256, 0, stream>>>((const unsigned int*)gbuf, csr, offs, cnt, dinv, b1,
                                     (unsigned int*)xbuf, N, 1);
    k_gemm<128><<<MB, 256, 0, stream>>>(xbuf, w2t, dinv, gbuf, N);
    k_agg128<<<AB, 256, 0, stream>>>((const unsigned int*)gbuf, csr, offs, cnt, dinv, b2,
                                     (unsigned int*)xbuf, N, 1);
    k_gemm3<<<MB, 256, 0, stream>>>(xbuf, W3, dinv, g3, N);
    k_agg9<<<AB9, 256, 0, stream>>>((const unsigned int*)g3, csr, offs, cnt, dinv, b3, out, N);
}

// Round 9
// 501.236 us; speedup vs baseline: 1.2623x; 1.2623x over previous
//
#include <hip/hip_runtime.h>
#include <hip/hip_bf16.h>

typedef __attribute__((ext_vector_type(8))) short bf16x8;
typedef __attribute__((ext_vector_type(4))) float f32x4;

#define BSH 8
#define BNODES 256  // nodes per bucket = 1 << BSH

__device__ __forceinline__ unsigned short f2bf(float f) {
    union { float f; unsigned int u; } x; x.f = f;
    unsigned int u = x.u;
    unsigned int r = (u + 0x7fffu + ((u >> 16) & 1u)) >> 16;  // RNE
    return (unsigned short)r;
}
__device__ __forceinline__ float bf_lo(unsigned int v) { return __uint_as_float(v << 16); }
__device__ __forceinline__ float bf_hi(unsigned int v) { return __uint_as_float(v & 0xffff0000u); }

__device__ __forceinline__ void gll16(const void* g, void* l) {
    __builtin_amdgcn_global_load_lds(
        (const __attribute__((address_space(1))) unsigned int*)g,
        (__attribute__((address_space(3))) unsigned int*)l, 16, 0, 0);
}

template <int N> __device__ __forceinline__ void waitvm() {
    if constexpr (N == 0) asm volatile("s_waitcnt vmcnt(0)" ::: "memory");
    else if constexpr (N == 4) asm volatile("s_waitcnt vmcnt(4)" ::: "memory");
    else if constexpr (N == 6) asm volatile("s_waitcnt vmcnt(6)" ::: "memory");
    else static_assert(N == 0, "unhandled vmcnt");
}

// ---------------- CSR build: binned, write-locality-aware ----------------

__global__ void k_zero(int* p, int n) {
    int i = blockIdx.x * 256 + threadIdx.x;
    if (i < n) p[i] = 0;
}

__global__ __launch_bounds__(256) void kA_hist(const int* __restrict__ dst, int* bhist,
                                               int E, int nbkt) {
    __shared__ int h[512];
    for (int i = threadIdx.x; i < 512; i += 256) h[i] = 0;
    __syncthreads();
    int stride = gridDim.x * 256;
    int n4 = E >> 2;
    for (int i = blockIdx.x * 256 + threadIdx.x; i < n4; i += stride) {
        int4 d = ((const int4*)dst)[i];
        atomicAdd(&h[d.x >> BSH], 1);
        atomicAdd(&h[d.y >> BSH], 1);
        atomicAdd(&h[d.z >> BSH], 1);
        atomicAdd(&h[d.w >> BSH], 1);
    }
    for (int i = (n4 << 2) + blockIdx.x * 256 + threadIdx.x; i < E; i += stride)
        atomicAdd(&h[dst[i] >> BSH], 1);
    __syncthreads();
    for (int i = threadIdx.x; i < nbkt; i += 256)
        if (h[i]) atomicAdd(&bhist[i], h[i]);
}

__global__ void kA_scan(const int* bhist, int* bbase, int* bcur, int nbkt) {
    __shared__ int s[512];
    int t = threadIdx.x;
    int v = (t < nbkt) ? bhist[t] : 0;
    s[t] = v;
    __syncthreads();
    for (int o = 1; o < 512; o <<= 1) {
        int x = (t >= o) ? s[t - o] : 0;
        __syncthreads();
        s[t] += x;
        __syncthreads();
    }
    if (t < nbkt) { bbase[t] = s[t] - v; bcur[t] = s[t] - v; }
    if (t == nbkt - 1) bbase[nbkt] = s[t];
}

#define TPE 16
__global__ __launch_bounds__(256) void kA_scatter(const int* __restrict__ src,
                                                  const int* __restrict__ dst,
                                                  int* bcur, unsigned int* pairs,
                                                  int E, int nbkt) {
    __shared__ int hist[512];
    __shared__ int base[512];
    const int tid = threadIdx.x;
    const int t0 = blockIdx.x * (256 * TPE);
    for (int i = tid; i < 512; i += 256) hist[i] = 0;
    __syncthreads();

    int es[TPE], ed[TPE], rk[TPE];
    bool valid[TPE];
    if (t0 + 256 * TPE <= E) {
        const int4* s4 = (const int4*)(src + t0 + tid * TPE);
        const int4* d4 = (const int4*)(dst + t0 + tid * TPE);
#pragma unroll
        for (int j = 0; j < TPE / 4; j++) {
            int4 a = s4[j], b = d4[j];
            es[4 * j + 0] = a.x; es[4 * j + 1] = a.y; es[4 * j + 2] = a.z; es[4 * j + 3] = a.w;
            ed[4 * j + 0] = b.x; ed[4 * j + 1] = b.y; ed[4 * j + 2] = b.z; ed[4 * j + 3] = b.w;
            valid[4 * j + 0] = valid[4 * j + 1] = valid[4 * j + 2] = valid[4 * j + 3] = true;
        }
    } else {
#pragma unroll
        for (int j = 0; j < TPE; j++) {
            int e = t0 + tid * TPE + j;
            valid[j] = (e < E);
            es[j] = valid[j] ? src[e] : 0;
            ed[j] = valid[j] ? dst[e] : 0;
        }
    }
#pragma unroll
    for (int j = 0; j < TPE; j++)
        if (valid[j]) rk[j] = atomicAdd(&hist[ed[j] >> BSH], 1);
    __syncthreads();
    for (int i = tid; i < nbkt; i += 256) {
        int c = hist[i];
        base[i] = c ? atomicAdd(&bcur[i], c) : 0;
    }
    __syncthreads();
#pragma unroll
    for (int j = 0; j < TPE; j++) {
        if (valid[j]) {
            int b = ed[j] >> BSH;
            unsigned int p = ((unsigned int)(ed[j] & (BNODES - 1)) << 24) | (unsigned int)es[j];
            pairs[base[b] + rk[j]] = p;
        }
    }
}

__global__ __launch_bounds__(512) void kB_group(const unsigned int* __restrict__ pairs,
                                                const int* __restrict__ bbase,
                                                int* csr, int* offs, int* cnt, float* dinv,
                                                int N, int nbkt) {
    int b = blockIdx.x;
    int p0 = bbase[b], p1 = bbase[b + 1];
    int node0 = b << BSH;
    int nn = min(BNODES, N - node0);
    __shared__ int lcnt[BNODES];
    __shared__ int ss[BNODES];
    __shared__ int lcur[BNODES];
    int t = threadIdx.x;
    if (t < BNODES) lcnt[t] = 0;
    __syncthreads();
    for (int i = p0 + t; i < p1; i += 512)
        atomicAdd(&lcnt[pairs[i] >> 24], 1);
    __syncthreads();
    int v = (t < BNODES) ? lcnt[t] : 0;
    if (t < BNODES) ss[t] = v;
    __syncthreads();
    for (int o = 1; o < BNODES; o <<= 1) {
        int x = (t >= o && t < BNODES) ? ss[t - o] : 0;
        __syncthreads();
        if (t < BNODES) ss[t] += x;
        __syncthreads();
    }
    if (t < nn) {
        int o = p0 + ss[t] - v;
        offs[node0 + t] = o;
        cnt[node0 + t] = v;
        dinv[node0 + t] = rsqrtf((float)(v + 1));
        lcur[t] = o;
    }
    __syncthreads();
    for (int i = p0 + t; i < p1; i += 512) {
        unsigned int p = pairs[i];
        int pos = atomicAdd(&lcur[p >> 24], 1);
        csr[pos] = (int)(p & 0xFFFFFFu);
    }
}

// W1 [1024][128] + W2 [128][128] fp32 -> transposed bf16 in one launch
__global__ void k_wt2(const float* __restrict__ W1, unsigned short* w1t,
                      const float* __restrict__ W2, unsigned short* w2t) {
    int i = blockIdx.x * 256 + threadIdx.x;
    if (i < 1024 * 128) {
        int k = i >> 7, c = i & 127;
        w1t[c * 1024 + k] = f2bf(W1[i]);
    } else {
        int j = i - 1024 * 128;
        if (j < 128 * 128) {
            int k = j >> 7, c = j & 127;
            w2t[c * 128 + k] = f2bf(W2[j]);
        }
    }
}

// ---------------- GEMM (M x K) @ (K x 128) -> g = (XW)*dinv, bf16 ----------------
// Round-7 3-buffer counted-vmcnt pipeline + LDS slot-SWIZZLE (rule #21: linear
// LDS dest for gll16, permute the per-lane GLOBAL source slot, apply the same
// permutation on the ds_read side).
//   f32 A tile (row=128B=bank period): slot' = (slot + (row&7)) & 7   (was 16-way)
//   bf16 A/B tile (row=64B):           slot' = (slot + (row>>2)) & 3  (was 8-way)
// -> 2 lanes/bank per phase = conflict-free (m136).

template <int K, bool IN_F32>
__global__ __launch_bounds__(256) void k_gemm(const void* __restrict__ Xv,
                                              const unsigned short* __restrict__ Wt,
                                              const float* __restrict__ dinv,
                                              unsigned short* __restrict__ G, int M) {
    constexpr int ABYTES = IN_F32 ? 128 * 32 * 4 : 128 * 32 * 2;  // per buffer
    constexpr int BBYTES = 128 * 32 * 2;
    constexpr int NT = K / 32;
    constexpr int NBUF = 3;
    constexpr int L = IN_F32 ? 6 : 4;
    static_assert(NT >= 3, "pipeline needs >=3 tiles");
    __shared__ char smem[NBUF * (ABYTES + BBYTES)];

    const int tid = threadIdx.x;
    const int m0 = blockIdx.x * 128;
    const int w = tid >> 6, l = tid & 63, r = l & 15, kg = l >> 4;
    const int wb0 = tid & ~63;

    auto stage = [&](int buf, int k0) {
        if (IN_F32) {
            const float* X = (const float*)Xv;
            char* ab = smem + buf * ABYTES;
#pragma unroll
            for (int i = 0; i < 4; i++) {
                int wb = i * 256 + wb0;
                int c = wb + l;
                int row = c >> 3, slot = c & 7;          // 8 x 16B slots per row
                int g = (slot - (row & 7)) & 7;          // inverse swizzle on source
                int srow = m0 + row; if (srow >= M) srow = M - 1;
                gll16(X + (size_t)srow * K + k0 + g * 4, ab + (size_t)wb * 16);
            }
        } else {
            const unsigned short* X = (const unsigned short*)Xv;
            char* ab = smem + buf * ABYTES;
#pragma unroll
            for (int i = 0; i < 2; i++) {
                int wb = i * 256 + wb0;
                int c = wb + l;
                int row = c >> 2, slot = c & 3;          // 4 x 16B slots per row
                int g = (slot - (row >> 2)) & 3;
                int srow = m0 + row; if (srow >= M) srow = M - 1;
                gll16(X + (size_t)srow * K + k0 + g * 8, ab + (size_t)wb * 16);
            }
        }
        {
            char* bb = smem + NBUF * ABYTES + buf * BBYTES;
#pragma unroll
            for (int i = 0; i < 2; i++) {
                int wb = i * 256 + wb0;
                int c = wb + l;
                int row = c >> 2, slot = c & 3;
                int g = (slot - (row >> 2)) & 3;
                gll16(Wt + (size_t)row * K + k0 + g * 8, bb + (size_t)wb * 16);
            }
        }
    };

    f32x4 acc[2][8];
#pragma unroll
    for (int mt = 0; mt < 2; mt++)
#pragma unroll
        for (int ct = 0; ct < 8; ct++) acc[mt][ct] = (f32x4){0.f, 0.f, 0.f, 0.f};

    auto compute = [&](int buf) {
        bf16x8 af[2], bfr[8];
        if (IN_F32) {
            const float* ab = (const float*)(smem + buf * ABYTES);
#pragma unroll
            for (int mt = 0; mt < 2; mt++) {
                int row = w * 32 + mt * 16 + r;
                int p = row & 7;
                int s0 = (2 * kg + p) & 7, s1 = (2 * kg + 1 + p) & 7;
                float4 f0 = *(const float4*)(ab + row * 32 + s0 * 4);
                float4 f1 = *(const float4*)(ab + row * 32 + s1 * 4);
                union { bf16x8 v; unsigned short u[8]; } a;
                a.u[0] = f2bf(f0.x); a.u[1] = f2bf(f0.y); a.u[2] = f2bf(f0.z); a.u[3] = f2bf(f0.w);
                a.u[4] = f2bf(f1.x); a.u[5] = f2bf(f1.y); a.u[6] = f2bf(f1.z); a.u[7] = f2bf(f1.w);
                af[mt] = a.v;
            }
        } else {
            const unsigned short* ab = (const unsigned short*)(smem + buf * ABYTES);
#pragma unroll
            for (int mt = 0; mt < 2; mt++) {
                int row = w * 32 + mt * 16 + r;
                int s = (kg + (row >> 2)) & 3;
                af[mt] = *(const bf16x8*)(ab + row * 32 + s * 8);
            }
        }
        {
            const unsigned short* bb = (const unsigned short*)(smem + NBUF * ABYTES + buf * BBYTES);
#pragma unroll
            for (int ct = 0; ct < 8; ct++) {
                int rowb = ct * 16 + r;
                int s = (kg + (rowb >> 2)) & 3;
                bfr[ct] = *(const bf16x8*)(bb + rowb * 32 + s * 8);
            }
        }
#pragma unroll
        for (int mt = 0; mt < 2; mt++)
#pragma unroll
            for (int ct = 0; ct < 8; ct++)
                acc[mt][ct] = __builtin_amdgcn_mfma_f32_16x16x32_bf16(af[mt], bfr[ct], acc[mt][ct], 0, 0, 0);
    };

    stage(0, 0);
    stage(1, 32);

    int cur = 0;
    for (int t = 0; t < NT - 2; ++t) {
        int nb = cur + 2; if (nb >= NBUF) nb -= NBUF;
        waitvm<L>();
        __builtin_amdgcn_s_barrier();
        stage(nb, (t + 2) * 32);
        compute(cur);
        cur = (cur + 1 == NBUF) ? 0 : cur + 1;
    }
    waitvm<L>();
    __builtin_amdgcn_s_barrier();
    compute(cur);
    cur = (cur + 1 == NBUF) ? 0 : cur + 1;
    waitvm<0>();
    __builtin_amdgcn_s_barrier();
    compute(cur);

    // epilogue: C/D layout col = lane&15, row = 4*(lane>>4) + reg  [m89-verified]
#pragma unroll
    for (int mt = 0; mt < 2; mt++) {
        int rbase = m0 + w * 32 + mt * 16 + kg * 4;
        float dv[4];
#pragma unroll
        for (int q = 0; q < 4; q++) dv[q] = (rbase + q < M) ? dinv[rbase + q] : 0.f;
#pragma unroll
        for (int ct = 0; ct < 8; ct++) {
#pragma unroll
            for (int q = 0; q < 4; q++) {
                int gr = rbase + q;
                if (gr < M) G[(size_t)gr * 128 + ct * 16 + r] = f2bf(acc[mt][ct][q] * dv[q]);
            }
        }
    }
}

// ---------------- GEMM3: [M][128]bf16 @ [128][9]f32 -> g3 [M][16]bf16 (padded) ----------------

__global__ __launch_bounds__(256) void k_gemm3(const unsigned short* X3, const float* W3,
                                               const float* dinv, unsigned short* G3, int M) {
    __shared__ unsigned short sx[128 * 136];
    __shared__ float sw[128 * 9];
    int tid = threadIdx.x;
    int m0 = blockIdx.x * 128;
#pragma unroll
    for (int p = 0; p < 8; p++) {
        int idx = p * 256 + tid;
        int row = idx >> 4, c8 = idx & 15;
        uint4 v = make_uint4(0u, 0u, 0u, 0u);
        if (m0 + row < M) v = *(const uint4*)(X3 + (size_t)(m0 + row) * 128 + c8 * 8);
        *(uint4*)&sx[row * 136 + c8 * 8] = v;
    }
    for (int i = tid; i < 128 * 9; i += 256) sw[i] = W3[i];
    __syncthreads();

    int r = tid >> 1, h = tid & 1;
    float acc[9];
#pragma unroll
    for (int c = 0; c < 9; c++) acc[c] = 0.f;
    for (int kk = 0; kk < 64; kk++) {
        int k = h * 64 + kk;
        float xv = __uint_as_float(((unsigned int)sx[r * 136 + k]) << 16);
#pragma unroll
        for (int c = 0; c < 9; c++) acc[c] += xv * sw[k * 9 + c];
    }
#pragma unroll
    for (int c = 0; c < 9; c++) acc[c] += __shfl_xor(acc[c], 1);
    int gr = m0 + r;
    if (h == 0 && gr < M) {
        float dv = dinv[gr];
#pragma unroll
        for (int c = 0; c < 9; c++) G3[(size_t)gr * 16 + c] = f2bf(acc[c] * dv);
#pragma unroll
        for (int c = 9; c < 16; c++) G3[(size_t)gr * 16 + c] = 0;
    }
}

// ---------------- aggregation, 128-dim: LDS-staged csr, 8-deep gather pipeline ----------------

#define A128_CAP 1024

__global__ __launch_bounds__(256) void k_agg128(const unsigned int* __restrict__ gv,
                                                const int* __restrict__ csr,
                                                const int* __restrict__ offs,
                                                const int* __restrict__ cnt,
                                                const float* __restrict__ dinv,
                                                const float* __restrict__ bias,
                                                unsigned int* xout, int N, int do_relu) {
    __shared__ int sidx[A128_CAP];
    const int tid = threadIdx.x;
    const int n0 = blockIdx.x * 4;
    const int nlast = min(n0 + 3, N - 1);
    const int base = offs[n0];
    const int tot = offs[nlast] + cnt[nlast] - base;
    const bool lds_ok = (tot <= A128_CAP);
    if (lds_ok)
        for (int i = tid; i < tot; i += 256) sidx[i] = csr[base + i];
    __syncthreads();

    const int node = n0 + (tid >> 6);
    if (node >= N) return;
    const int l = tid & 63;
    const int ne = cnt[node];
    const int st = offs[node] - base;

    unsigned int u = gv[node * 64 + l];
    float a0 = bf_lo(u), a1 = bf_hi(u);
    int e = 0;
    if (lds_ok) {
        for (; e + 8 <= ne; e += 8) {
            int s0 = sidx[st + e], s1 = sidx[st + e + 1];
            int s2 = sidx[st + e + 2], s3 = sidx[st + e + 3];
            int s4 = sidx[st + e + 4], s5 = sidx[st + e + 5];
            int s6 = sidx[st + e + 6], s7 = sidx[st + e + 7];
            unsigned int v0 = gv[s0 * 64 + l], v1 = gv[s1 * 64 + l];
            unsigned int v2 = gv[s2 * 64 + l], v3 = gv[s3 * 64 + l];
            unsigned int v4 = gv[s4 * 64 + l], v5 = gv[s5 * 64 + l];
            unsigned int v6 = gv[s6 * 64 + l], v7 = gv[s7 * 64 + l];
            a0 += bf_lo(v0); a1 += bf_hi(v0);
            a0 += bf_lo(v1); a1 += bf_hi(v1);
            a0 += bf_lo(v2); a1 += bf_hi(v2);
            a0 += bf_lo(v3); a1 += bf_hi(v3);
            a0 += bf_lo(v4); a1 += bf_hi(v4);
            a0 += bf_lo(v5); a1 += bf_hi(v5);
            a0 += bf_lo(v6); a1 += bf_hi(v6);
            a0 += bf_lo(v7); a1 += bf_hi(v7);
        }
        for (; e < ne; e++) {
            unsigned int v = gv[sidx[st + e] * 64 + l];
            a0 += bf_lo(v); a1 += bf_hi(v);
        }
    } else {
        const int gst = offs[node];
        for (; e < ne; e++) {
            unsigned int v = gv[csr[gst + e] * 64 + l];
            a0 += bf_lo(v); a1 += bf_hi(v);
        }
    }
    float dv = dinv[node];
    float o0 = fmaf(dv, a0, bias[2 * l]);
    float o1 = fmaf(dv, a1, bias[2 * l + 1]);
    if (do_relu) { o0 = fmaxf(o0, 0.f); o1 = fmaxf(o1, 0.f); }
    xout[node * 64 + l] = (unsigned int)f2bf(o0) | ((unsigned int)f2bf(o1) << 16);
}

// ---------------- aggregation, 9-dim + log_softmax: 8 lanes/node, 32 nodes/block ----------------

#define A9_CAP 3072

__global__ __launch_bounds__(256) void k_agg9(const unsigned int* __restrict__ g3v,
                                              const int* __restrict__ csr,
                                              const int* __restrict__ offs,
                                              const int* __restrict__ cnt,
                                              const float* __restrict__ dinv,
                                              const float* __restrict__ b3,
                                              float* out, int N) {
    __shared__ int sidx[A9_CAP];
    const int tid = threadIdx.x;
    const int n0 = blockIdx.x * 32;
    const int nlast = min(n0 + 31, N - 1);
    const int base = offs[n0];
    const int tot = offs[nlast] + cnt[nlast] - base;
    const bool lds_ok = (tot <= A9_CAP);
    if (lds_ok)
        for (int i = tid; i < tot; i += 256) sidx[i] = csr[base + i];
    __syncthreads();

    const int node = n0 + (tid >> 3);
    if (node >= N) return;
    const int jl = tid & 7;
    const int ne = cnt[node];

    unsigned int u = g3v[node * 8 + jl];
    float a0 = bf_lo(u), a1 = bf_hi(u);
    int e = 0;
    if (lds_ok) {
        const int st = offs[node] - base;
        for (; e + 4 <= ne; e += 4) {
            int s0 = sidx[st + e], s1 = sidx[st + e + 1];
            int s2 = sidx[st + e + 2], s3 = sidx[st + e + 3];
            unsigned int v0 = g3v[s0 * 8 + jl], v1 = g3v[s1 * 8 + jl];
            unsigned int v2 = g3v[s2 * 8 + jl], v3 = g3v[s3 * 8 + jl];
            a0 += bf_lo(v0); a1 += bf_hi(v0);
            a0 += bf_lo(v1); a1 += bf_hi(v1);
            a0 += bf_lo(v2); a1 += bf_hi(v2);
            a0 += bf_lo(v3); a1 += bf_hi(v3);
        }
        for (; e < ne; e++) {
            unsigned int v = g3v[sidx[st + e] * 8 + jl];
            a0 += bf_lo(v); a1 += bf_hi(v);
        }
    } else {
        const int gst = offs[node];
        for (; e < ne; e++) {
            unsigned int v = g3v[csr[gst + e] * 8 + jl];
            a0 += bf_lo(v); a1 += bf_hi(v);
        }
    }
    float dv = dinv[node];
    int c0 = 2 * jl, c1 = 2 * jl + 1;
    float o0 = (c0 < 9) ? fmaf(dv, a0, b3[c0]) : -INFINITY;
    float o1 = (c1 < 9) ? fmaf(dv, a1, b3[c1]) : -INFINITY;
    float m = fmaxf(o0, o1);
    for (int d = 1; d < 8; d <<= 1) m = fmaxf(m, __shfl_xor(m, d));
    float s = 0.f;
    if (c0 < 9) s += expf(o0 - m);
    if (c1 < 9) s += expf(o1 - m);
    for (int d = 1; d < 8; d <<= 1) s += __shfl_xor(s, d);
    float ls = m + logf(s);
    if (c0 < 9) out[(size_t)node * 9 + c0] = o0 - ls;
    if (c1 < 9) out[(size_t)node * 9 + c1] = o1 - ls;
}

// ---------------- launch ----------------

extern "C" void kernel_launch(void* const* d_in, const int* in_sizes, int n_in,
                              void* d_out, int out_size, void* d_ws, size_t ws_size,
                              hipStream_t stream) {
    const float* x = (const float*)d_in[0];
    const int* ei = (const int*)d_in[1];
    const float* W1 = (const float*)d_in[2];
    const float* b1 = (const float*)d_in[3];
    const float* W2 = (const float*)d_in[4];
    const float* b2 = (const float*)d_in[5];
    const float* W3 = (const float*)d_in[6];
    const float* b3 = (const float*)d_in[7];
    float* out = (float*)d_out;

    const int N = in_sizes[0] / 1024;
    const int E = in_sizes[1] / 2;
    const int* src = ei;
    const int* dst = ei + E;
    const int nbkt = (N + BNODES - 1) >> BSH;

    char* ws = (char*)d_ws;
    size_t off = 0;
    auto alloc = [&](size_t bytes) -> char* {
        char* p = ws + off;
        off += (bytes + 255) & ~(size_t)255;
        return p;
    };
    int* cnt = (int*)alloc((size_t)N * 4);
    int* offs = (int*)alloc((size_t)N * 4);
    float* dinv = (float*)alloc((size_t)N * 4);
    int* bhist = (int*)alloc(520 * 4);
    int* bbase = (int*)alloc(520 * 4);
    int* bcur = (int*)alloc(520 * 4);
    unsigned int* pairs = (unsigned int*)alloc((size_t)E * 4);
    int* csr = (int*)alloc((size_t)E * 4);
    unsigned short* w1t = (unsigned short*)alloc(128 * 1024 * 2);
    unsigned short* w2t = (unsigned short*)alloc(128 * 128 * 2);
    unsigned short* gbuf = (unsigned short*)alloc((size_t)N * 128 * 2);
    unsigned short* xbuf = (unsigned short*)alloc((size_t)N * 128 * 2);
    unsigned short* g3 = (unsigned short*)alloc((size_t)N * 16 * 2);

    const int MB = (N + 127) / 128;
    const int AB = (N + 3) / 4;
    const int AB9 = (N + 31) / 32;
    const int SB = (E + 256 * TPE - 1) / (256 * TPE);
    const int WB = (1024 * 128 + 128 * 128 + 255) / 256;

    k_zero<<<3, 256, 0, stream>>>(bhist, 520);
    kA_hist<<<512, 256, 0, stream>>>(dst, bhist, E, nbkt);
    kA_scan<<<1, 512, 0, stream>>>(bhist, bbase, bcur, nbkt);
    kA_scatter<<<SB, 256, 0, stream>>>(src, dst, bcur, pairs, E, nbkt);
    kB_group<<<nbkt, 512, 0, stream>>>(pairs, bbase, csr, offs, cnt, dinv, N, nbkt);
    k_wt2<<<WB, 256, 0, stream>>>(W1, w1t, W2, w2t);

    k_gemm<1024, true><<<MB, 256, 0, stream>>>((const void*)x, w1t, dinv, gbuf, N);
    k_agg128<<<AB, 256, 0, stream>>>((const unsigned int*)gbuf, csr, offs, cnt, dinv, b1,
                                     (unsigned int*)xbuf, N, 1);
    k_gemm<128, false><<<MB, 256, 0, stream>>>((const void*)xbuf, w2t, dinv, gbuf, N);
    k_agg128<<<AB, 256, 0, stream>>>((const unsigned int*)gbuf, csr, offs, cnt, dinv, b2,
                                     (unsigned int*)xbuf, N, 1);
    k_gemm3<<<MB, 256, 0, stream>>>(xbuf, W3, dinv, g3, N);
    k_agg9<<<AB9, 256, 0, stream>>>((const unsigned int*)g3, csr, offs, cnt, dinv, b3, out, N);
}

// Round 10
// 487.523 us; speedup vs baseline: 1.2978x; 1.0281x over previous
//
#include <hip/hip_runtime.h>
#include <hip/hip_bf16.h>

typedef __attribute__((ext_vector_type(8))) short bf16x8;
typedef __attribute__((ext_vector_type(4))) float f32x4;

#define BSH 8
#define BNODES 256   // nodes per bucket = 1 << BSH
#define BCAP 16384   // slab capacity per bucket (max bucket ~8.6k for E=3.2M, N=100k)

__device__ __forceinline__ unsigned short f2bf(float f) {
    union { float f; unsigned int u; } x; x.f = f;
    unsigned int u = x.u;
    unsigned int r = (u + 0x7fffu + ((u >> 16) & 1u)) >> 16;  // RNE
    return (unsigned short)r;
}
__device__ __forceinline__ float bf_lo(unsigned int v) { return __uint_as_float(v << 16); }
__device__ __forceinline__ float bf_hi(unsigned int v) { return __uint_as_float(v & 0xffff0000u); }

__device__ __forceinline__ void gll16(const void* g, void* l) {
    __builtin_amdgcn_global_load_lds(
        (const __attribute__((address_space(1))) unsigned int*)g,
        (__attribute__((address_space(3))) unsigned int*)l, 16, 0, 0);
}

template <int N> __device__ __forceinline__ void waitvm() {
    if constexpr (N == 0) asm volatile("s_waitcnt vmcnt(0)" ::: "memory");
    else if constexpr (N == 4) asm volatile("s_waitcnt vmcnt(4)" ::: "memory");
    else if constexpr (N == 6) asm volatile("s_waitcnt vmcnt(6)" ::: "memory");
    else static_assert(N == 0, "unhandled vmcnt");
}

// ---------------- CSR build: single-pass bucketed scatter (no hist/scan) ----------------

__global__ void k_zero(int* p, int n) {
    int i = blockIdx.x * 256 + threadIdx.x;
    if (i < n) p[i] = 0;
}

#define TPE 16
// Tile of 4096 edges per block: LDS rank per bucket, one global atomicAdd per
// (block,bucket) claims a contiguous run in the bucket's fixed slab.
__global__ __launch_bounds__(256) void kA_scatter(const int* __restrict__ src,
                                                  const int* __restrict__ dst,
                                                  int* gcur, unsigned int* pairs,
                                                  int E, int nbkt) {
    __shared__ int hist[512];
    __shared__ int base[512];
    const int tid = threadIdx.x;
    const int t0 = blockIdx.x * (256 * TPE);
    for (int i = tid; i < 512; i += 256) hist[i] = 0;
    __syncthreads();

    int es[TPE], ed[TPE], rk[TPE];
    bool valid[TPE];
    if (t0 + 256 * TPE <= E) {
        const int4* s4 = (const int4*)(src + t0 + tid * TPE);
        const int4* d4 = (const int4*)(dst + t0 + tid * TPE);
#pragma unroll
        for (int j = 0; j < TPE / 4; j++) {
            int4 a = s4[j], b = d4[j];
            es[4 * j + 0] = a.x; es[4 * j + 1] = a.y; es[4 * j + 2] = a.z; es[4 * j + 3] = a.w;
            ed[4 * j + 0] = b.x; ed[4 * j + 1] = b.y; ed[4 * j + 2] = b.z; ed[4 * j + 3] = b.w;
            valid[4 * j + 0] = valid[4 * j + 1] = valid[4 * j + 2] = valid[4 * j + 3] = true;
        }
    } else {
#pragma unroll
        for (int j = 0; j < TPE; j++) {
            int e = t0 + tid * TPE + j;
            valid[j] = (e < E);
            es[j] = valid[j] ? src[e] : 0;
            ed[j] = valid[j] ? dst[e] : 0;
        }
    }
#pragma unroll
    for (int j = 0; j < TPE; j++)
        if (valid[j]) rk[j] = atomicAdd(&hist[ed[j] >> BSH], 1);
    __syncthreads();
    for (int i = tid; i < nbkt; i += 256) {
        int c = hist[i];
        base[i] = c ? atomicAdd(&gcur[i], c) : 0;
    }
    __syncthreads();
#pragma unroll
    for (int j = 0; j < TPE; j++) {
        if (valid[j]) {
            int b = ed[j] >> BSH;
            int pos = base[b] + rk[j];
            if (pos < BCAP) {
                unsigned int p = ((unsigned int)(ed[j] & (BNODES - 1)) << 24) | (unsigned int)es[j];
                pairs[(size_t)b * BCAP + pos] = p;
            }
        }
    }
}

// per-bucket grouping in the slab; emits offs/cnt/dinv pointing into padded csr
__global__ __launch_bounds__(512) void kB_group(const unsigned int* __restrict__ pairs,
                                                const int* __restrict__ gcur,
                                                int* csr, int* offs, int* cnt, float* dinv,
                                                int N, int nbkt) {
    int b = blockIdx.x;
    int p0 = b * BCAP;
    int psz = min(gcur[b], BCAP);
    int node0 = b << BSH;
    int nn = min(BNODES, N - node0);
    __shared__ int lcnt[BNODES];
    __shared__ int ss[BNODES];
    __shared__ int lcur[BNODES];
    int t = threadIdx.x;
    if (t < BNODES) lcnt[t] = 0;
    __syncthreads();
    for (int i = t; i < psz; i += 512)
        atomicAdd(&lcnt[pairs[p0 + i] >> 24], 1);
    __syncthreads();
    int v = (t < BNODES) ? lcnt[t] : 0;
    if (t < BNODES) ss[t] = v;
    __syncthreads();
    for (int o = 1; o < BNODES; o <<= 1) {
        int x = (t >= o && t < BNODES) ? ss[t - o] : 0;
        __syncthreads();
        if (t < BNODES) ss[t] += x;
        __syncthreads();
    }
    if (t < nn) {
        int o = p0 + ss[t] - v;
        offs[node0 + t] = o;
        cnt[node0 + t] = v;
        dinv[node0 + t] = rsqrtf((float)(v + 1));
        lcur[t] = o;
    }
    __syncthreads();
    for (int i = t; i < psz; i += 512) {
        unsigned int p = pairs[p0 + i];
        int pos = atomicAdd(&lcur[p >> 24], 1);
        csr[pos] = (int)(p & 0xFFFFFFu);
    }
}

// W1 [1024][128] + W2 [128][128] fp32 -> transposed bf16 in one launch
__global__ void k_wt2(const float* __restrict__ W1, unsigned short* w1t,
                      const float* __restrict__ W2, unsigned short* w2t) {
    int i = blockIdx.x * 256 + threadIdx.x;
    if (i < 1024 * 128) {
        int k = i >> 7, c = i & 127;
        w1t[c * 1024 + k] = f2bf(W1[i]);
    } else {
        int j = i - 1024 * 128;
        if (j < 128 * 128) {
            int k = j >> 7, c = j & 127;
            w2t[c * 128 + k] = f2bf(W2[j]);
        }
    }
}

// ---------------- GEMM (M x K) @ (K x 128) -> g = (XW)*dinv, bf16 ----------------
// 3-buffer counted-vmcnt pipeline + source-side LDS slot swizzle (round-9 best).

template <int K, bool IN_F32>
__global__ __launch_bounds__(256) void k_gemm(const void* __restrict__ Xv,
                                              const unsigned short* __restrict__ Wt,
                                              const float* __restrict__ dinv,
                                              unsigned short* __restrict__ G, int M) {
    constexpr int ABYTES = IN_F32 ? 128 * 32 * 4 : 128 * 32 * 2;
    constexpr int BBYTES = 128 * 32 * 2;
    constexpr int NT = K / 32;
    constexpr int NBUF = 3;
    constexpr int L = IN_F32 ? 6 : 4;
    static_assert(NT >= 3, "pipeline needs >=3 tiles");
    __shared__ char smem[NBUF * (ABYTES + BBYTES)];

    const int tid = threadIdx.x;
    const int m0 = blockIdx.x * 128;
    const int w = tid >> 6, l = tid & 63, r = l & 15, kg = l >> 4;
    const int wb0 = tid & ~63;

    auto stage = [&](int buf, int k0) {
        if (IN_F32) {
            const float* X = (const float*)Xv;
            char* ab = smem + buf * ABYTES;
#pragma unroll
            for (int i = 0; i < 4; i++) {
                int wb = i * 256 + wb0;
                int c = wb + l;
                int row = c >> 3, slot = c & 7;
                int g = (slot - (row & 7)) & 7;
                int srow = m0 + row; if (srow >= M) srow = M - 1;
                gll16(X + (size_t)srow * K + k0 + g * 4, ab + (size_t)wb * 16);
            }
        } else {
            const unsigned short* X = (const unsigned short*)Xv;
            char* ab = smem + buf * ABYTES;
#pragma unroll
            for (int i = 0; i < 2; i++) {
                int wb = i * 256 + wb0;
                int c = wb + l;
                int row = c >> 2, slot = c & 3;
                int g = (slot - (row >> 2)) & 3;
                int srow = m0 + row; if (srow >= M) srow = M - 1;
                gll16(X + (size_t)srow * K + k0 + g * 8, ab + (size_t)wb * 16);
            }
        }
        {
            char* bb = smem + NBUF * ABYTES + buf * BBYTES;
#pragma unroll
            for (int i = 0; i < 2; i++) {
                int wb = i * 256 + wb0;
                int c = wb + l;
                int row = c >> 2, slot = c & 3;
                int g = (slot - (row >> 2)) & 3;
                gll16(Wt + (size_t)row * K + k0 + g * 8, bb + (size_t)wb * 16);
            }
        }
    };

    f32x4 acc[2][8];
#pragma unroll
    for (int mt = 0; mt < 2; mt++)
#pragma unroll
        for (int ct = 0; ct < 8; ct++) acc[mt][ct] = (f32x4){0.f, 0.f, 0.f, 0.f};

    auto compute = [&](int buf) {
        bf16x8 af[2], bfr[8];
        if (IN_F32) {
            const float* ab = (const float*)(smem + buf * ABYTES);
#pragma unroll
            for (int mt = 0; mt < 2; mt++) {
                int row = w * 32 + mt * 16 + r;
                int p = row & 7;
                int s0 = (2 * kg + p) & 7, s1 = (2 * kg + 1 + p) & 7;
                float4 f0 = *(const float4*)(ab + row * 32 + s0 * 4);
                float4 f1 = *(const float4*)(ab + row * 32 + s1 * 4);
                union { bf16x8 v; unsigned short u[8]; } a;
                a.u[0] = f2bf(f0.x); a.u[1] = f2bf(f0.y); a.u[2] = f2bf(f0.z); a.u[3] = f2bf(f0.w);
                a.u[4] = f2bf(f1.x); a.u[5] = f2bf(f1.y); a.u[6] = f2bf(f1.z); a.u[7] = f2bf(f1.w);
                af[mt] = a.v;
            }
        } else {
            const unsigned short* ab = (const unsigned short*)(smem + buf * ABYTES);
#pragma unroll
            for (int mt = 0; mt < 2; mt++) {
                int row = w * 32 + mt * 16 + r;
                int s = (kg + (row >> 2)) & 3;
                af[mt] = *(const bf16x8*)(ab + row * 32 + s * 8);
            }
        }
        {
            const unsigned short* bb = (const unsigned short*)(smem + NBUF * ABYTES + buf * BBYTES);
#pragma unroll
            for (int ct = 0; ct < 8; ct++) {
                int rowb = ct * 16 + r;
                int s = (kg + (rowb >> 2)) & 3;
                bfr[ct] = *(const bf16x8*)(bb + rowb * 32 + s * 8);
            }
        }
#pragma unroll
        for (int mt = 0; mt < 2; mt++)
#pragma unroll
            for (int ct = 0; ct < 8; ct++)
                acc[mt][ct] = __builtin_amdgcn_mfma_f32_16x16x32_bf16(af[mt], bfr[ct], acc[mt][ct], 0, 0, 0);
    };

    stage(0, 0);
    stage(1, 32);

    int cur = 0;
    for (int t = 0; t < NT - 2; ++t) {
        int nb = cur + 2; if (nb >= NBUF) nb -= NBUF;
        waitvm<L>();
        __builtin_amdgcn_s_barrier();
        stage(nb, (t + 2) * 32);
        compute(cur);
        cur = (cur + 1 == NBUF) ? 0 : cur + 1;
    }
    waitvm<L>();
    __builtin_amdgcn_s_barrier();
    compute(cur);
    cur = (cur + 1 == NBUF) ? 0 : cur + 1;
    waitvm<0>();
    __builtin_amdgcn_s_barrier();
    compute(cur);

    // epilogue: C/D layout col = lane&15, row = 4*(lane>>4) + reg  [m89-verified]
#pragma unroll
    for (int mt = 0; mt < 2; mt++) {
        int rbase = m0 + w * 32 + mt * 16 + kg * 4;
        float dv[4];
#pragma unroll
        for (int q = 0; q < 4; q++) dv[q] = (rbase + q < M) ? dinv[rbase + q] : 0.f;
#pragma unroll
        for (int ct = 0; ct < 8; ct++) {
#pragma unroll
            for (int q = 0; q < 4; q++) {
                int gr = rbase + q;
                if (gr < M) G[(size_t)gr * 128 + ct * 16 + r] = f2bf(acc[mt][ct][q] * dv[q]);
            }
        }
    }
}

// ---------------- GEMM3: [M][128]bf16 @ [128][9]f32 -> g3 [M][16]bf16 (padded) ----------------

__global__ __launch_bounds__(256) void k_gemm3(const unsigned short* X3, const float* W3,
                                               const float* dinv, unsigned short* G3, int M) {
    __shared__ unsigned short sx[128 * 136];
    __shared__ float sw[128 * 9];
    int tid = threadIdx.x;
    int m0 = blockIdx.x * 128;
#pragma unroll
    for (int p = 0; p < 8; p++) {
        int idx = p * 256 + tid;
        int row = idx >> 4, c8 = idx & 15;
        uint4 v = make_uint4(0u, 0u, 0u, 0u);
        if (m0 + row < M) v = *(const uint4*)(X3 + (size_t)(m0 + row) * 128 + c8 * 8);
        *(uint4*)&sx[row * 136 + c8 * 8] = v;
    }
    for (int i = tid; i < 128 * 9; i += 256) sw[i] = W3[i];
    __syncthreads();

    int r = tid >> 1, h = tid & 1;
    float acc[9];
#pragma unroll
    for (int c = 0; c < 9; c++) acc[c] = 0.f;
    for (int kk = 0; kk < 64; kk++) {
        int k = h * 64 + kk;
        float xv = __uint_as_float(((unsigned int)sx[r * 136 + k]) << 16);
#pragma unroll
        for (int c = 0; c < 9; c++) acc[c] += xv * sw[k * 9 + c];
    }
#pragma unroll
    for (int c = 0; c < 9; c++) acc[c] += __shfl_xor(acc[c], 1);
    int gr = m0 + r;
    if (h == 0 && gr < M) {
        float dv = dinv[gr];
#pragma unroll
        for (int c = 0; c < 9; c++) G3[(size_t)gr * 16 + c] = f2bf(acc[c] * dv);
#pragma unroll
        for (int c = 9; c < 16; c++) G3[(size_t)gr * 16 + c] = 0;
    }
}

// ---------------- aggregation, 128-dim: LDS-staged csr, 8-deep gather pipeline ----------------

#define A128_CAP 1024

__global__ __launch_bounds__(256) void k_agg128(const unsigned int* __restrict__ gv,
                                                const int* __restrict__ csr,
                                                const int* __restrict__ offs,
                                                const int* __restrict__ cnt,
                                                const float* __restrict__ dinv,
                                                const float* __restrict__ bias,
                                                unsigned int* xout, int N, int do_relu) {
    __shared__ int sidx[A128_CAP];
    const int tid = threadIdx.x;
    const int n0 = blockIdx.x * 4;
    const int nlast = min(n0 + 3, N - 1);
    const int base = offs[n0];
    const int tot = offs[nlast] + cnt[nlast] - base;
    const bool lds_ok = (tot <= A128_CAP);
    if (lds_ok)
        for (int i = tid; i < tot; i += 256) sidx[i] = csr[base + i];
    __syncthreads();

    const int node = n0 + (tid >> 6);
    if (node >= N) return;
    const int l = tid & 63;
    const int ne = cnt[node];
    const int st = offs[node] - base;

    unsigned int u = gv[node * 64 + l];
    float a0 = bf_lo(u), a1 = bf_hi(u);
    int e = 0;
    if (lds_ok) {
        for (; e + 8 <= ne; e += 8) {
            int s0 = sidx[st + e], s1 = sidx[st + e + 1];
            int s2 = sidx[st + e + 2], s3 = sidx[st + e + 3];
            int s4 = sidx[st + e + 4], s5 = sidx[st + e + 5];
            int s6 = sidx[st + e + 6], s7 = sidx[st + e + 7];
            unsigned int v0 = gv[s0 * 64 + l], v1 = gv[s1 * 64 + l];
            unsigned int v2 = gv[s2 * 64 + l], v3 = gv[s3 * 64 + l];
            unsigned int v4 = gv[s4 * 64 + l], v5 = gv[s5 * 64 + l];
            unsigned int v6 = gv[s6 * 64 + l], v7 = gv[s7 * 64 + l];
            a0 += bf_lo(v0); a1 += bf_hi(v0);
            a0 += bf_lo(v1); a1 += bf_hi(v1);
            a0 += bf_lo(v2); a1 += bf_hi(v2);
            a0 += bf_lo(v3); a1 += bf_hi(v3);
            a0 += bf_lo(v4); a1 += bf_hi(v4);
            a0 += bf_lo(v5); a1 += bf_hi(v5);
            a0 += bf_lo(v6); a1 += bf_hi(v6);
            a0 += bf_lo(v7); a1 += bf_hi(v7);
        }
        for (; e < ne; e++) {
            unsigned int v = gv[sidx[st + e] * 64 + l];
            a0 += bf_lo(v); a1 += bf_hi(v);
        }
    } else {
        const int gst = offs[node];
        for (; e < ne; e++) {
            unsigned int v = gv[csr[gst + e] * 64 + l];
            a0 += bf_lo(v); a1 += bf_hi(v);
        }
    }
    float dv = dinv[node];
    float o0 = fmaf(dv, a0, bias[2 * l]);
    float o1 = fmaf(dv, a1, bias[2 * l + 1]);
    if (do_relu) { o0 = fmaxf(o0, 0.f); o1 = fmaxf(o1, 0.f); }
    xout[node * 64 + l] = (unsigned int)f2bf(o0) | ((unsigned int)f2bf(o1) << 16);
}

// ---------------- aggregation, 9-dim + log_softmax: 8 lanes/node, 32 nodes/block ----------------

#define A9_CAP 3072

__global__ __launch_bounds__(256) void k_agg9(const unsigned int* __restrict__ g3v,
                                              const int* __restrict__ csr,
                                              const int* __restrict__ offs,
                                              const int* __restrict__ cnt,
                                              const float* __restrict__ dinv,
                                              const float* __restrict__ b3,
                                              float* out, int N) {
    __shared__ int sidx[A9_CAP];
    const int tid = threadIdx.x;
    const int n0 = blockIdx.x * 32;
    const int nlast = min(n0 + 31, N - 1);
    const int base = offs[n0];
    const int tot = offs[nlast] + cnt[nlast] - base;
    const bool lds_ok = (tot <= A9_CAP);
    if (lds_ok)
        for (int i = tid; i < tot; i += 256) sidx[i] = csr[base + i];
    __syncthreads();

    const int node = n0 + (tid >> 3);
    if (node >= N) return;
    const int jl = tid & 7;
    const int ne = cnt[node];

    unsigned int u = g3v[node * 8 + jl];
    float a0 = bf_lo(u), a1 = bf_hi(u);
    int e = 0;
    if (lds_ok) {
        const int st = offs[node] - base;
        for (; e + 4 <= ne; e += 4) {
            int s0 = sidx[st + e], s1 = sidx[st + e + 1];
            int s2 = sidx[st + e + 2], s3 = sidx[st + e + 3];
            unsigned int v0 = g3v[s0 * 8 + jl], v1 = g3v[s1 * 8 + jl];
            unsigned int v2 = g3v[s2 * 8 + jl], v3 = g3v[s3 * 8 + jl];
            a0 += bf_lo(v0); a1 += bf_hi(v0);
            a0 += bf_lo(v1); a1 += bf_hi(v1);
            a0 += bf_lo(v2); a1 += bf_hi(v2);
            a0 += bf_lo(v3); a1 += bf_hi(v3);
        }
        for (; e < ne; e++) {
            unsigned int v = g3v[sidx[st + e] * 8 + jl];
            a0 += bf_lo(v); a1 += bf_hi(v);
        }
    } else {
        const int gst = offs[node];
        for (; e < ne; e++) {
            unsigned int v = g3v[csr[gst + e] * 8 + jl];
            a0 += bf_lo(v); a1 += bf_hi(v);
        }
    }
    float dv = dinv[node];
    int c0 = 2 * jl, c1 = 2 * jl + 1;
    float o0 = (c0 < 9) ? fmaf(dv, a0, b3[c0]) : -INFINITY;
    float o1 = (c1 < 9) ? fmaf(dv, a1, b3[c1]) : -INFINITY;
    float m = fmaxf(o0, o1);
    for (int d = 1; d < 8; d <<= 1) m = fmaxf(m, __shfl_xor(m, d));
    float s = 0.f;
    if (c0 < 9) s += expf(o0 - m);
    if (c1 < 9) s += expf(o1 - m);
    for (int d = 1; d < 8; d <<= 1) s += __shfl_xor(s, d);
    float ls = m + logf(s);
    if (c0 < 9) out[(size_t)node * 9 + c0] = o0 - ls;
    if (c1 < 9) out[(size_t)node * 9 + c1] = o1 - ls;
}

// ---------------- launch ----------------

extern "C" void kernel_launch(void* const* d_in, const int* in_sizes, int n_in,
                              void* d_out, int out_size, void* d_ws, size_t ws_size,
                              hipStream_t stream) {
    const float* x = (const float*)d_in[0];
    const int* ei = (const int*)d_in[1];
    const float* W1 = (const float*)d_in[2];
    const float* b1 = (const float*)d_in[3];
    const float* W2 = (const float*)d_in[4];
    const float* b2 = (const float*)d_in[5];
    const float* W3 = (const float*)d_in[6];
    const float* b3 = (const float*)d_in[7];
    float* out = (float*)d_out;

    const int N = in_sizes[0] / 1024;
    const int E = in_sizes[1] / 2;
    const int* src = ei;
    const int* dst = ei + E;
    const int nbkt = (N + BNODES - 1) >> BSH;

    char* ws = (char*)d_ws;
    size_t off = 0;
    auto alloc = [&](size_t bytes) -> char* {
        char* p = ws + off;
        off += (bytes + 255) & ~(size_t)255;
        return p;
    };
    int* cnt = (int*)alloc((size_t)N * 4);
    int* offs = (int*)alloc((size_t)N * 4);
    float* dinv = (float*)alloc((size_t)N * 4);
    int* gcur = (int*)alloc(520 * 4);
    unsigned int* pairs = (unsigned int*)alloc((size_t)nbkt * BCAP * 4);
    int* csr = (int*)alloc((size_t)nbkt * BCAP * 4);
    unsigned short* w1t = (unsigned short*)alloc(128 * 1024 * 2);
    unsigned short* w2t = (unsigned short*)alloc(128 * 128 * 2);
    unsigned short* gbuf = (unsigned short*)alloc((size_t)N * 128 * 2);
    unsigned short* xbuf = (unsigned short*)alloc((size_t)N * 128 * 2);
    unsigned short* g3 = (unsigned short*)alloc((size_t)N * 16 * 2);

    const int MB = (N + 127) / 128;
    const int AB = (N + 3) / 4;
    const int AB9 = (N + 31) / 32;
    const int SB = (E + 256 * TPE - 1) / (256 * TPE);
    const int WB = (1024 * 128 + 128 * 128 + 255) / 256;

    k_zero<<<3, 256, 0, stream>>>(gcur, 520);
    kA_scatter<<<SB, 256, 0, stream>>>(src, dst, gcur, pairs, E, nbkt);
    kB_group<<<nbkt, 512, 0, stream>>>(pairs, gcur, csr, offs, cnt, dinv, N, nbkt);
    k_wt2<<<WB, 256, 0, stream>>>(W1, w1t, W2, w2t);

    k_gemm<1024, true><<<MB, 256, 0, stream>>>((const void*)x, w1t, dinv, gbuf, N);
    k_agg128<<<AB, 256, 0, stream>>>((const unsigned int*)gbuf, csr, offs, cnt, dinv, b1,
                                     (unsigned int*)xbuf, N, 1);
    k_gemm<128, false><<<MB, 256, 0, stream>>>((const void*)xbuf, w2t, dinv, gbuf, N);
    k_agg128<<<AB, 256, 0, stream>>>((const unsigned int*)gbuf, csr, offs, cnt, dinv, b2,
                                     (unsigned int*)xbuf, N, 1);
    k_gemm3<<<MB, 256, 0, stream>>>(xbuf, W3, dinv, g3, N);
    k_agg9<<<AB9, 256, 0, stream>>>((const unsigned int*)g3, csr, offs, cnt, dinv, b3, out, N);
}

// Round 11
// 483.599 us; speedup vs baseline: 1.3083x; 1.0081x over previous
//
#include <hip/hip_runtime.h>
#include <hip/hip_bf16.h>

typedef __attribute__((ext_vector_type(8))) short bf16x8;
typedef __attribute__((ext_vector_type(4))) float f32x4;

#define BSH 8
#define BNODES 256   // nodes per bucket = 1 << BSH
#define BCAP 16384   // slab capacity per bucket (max bucket ~8.6k for E=3.2M, N=100k)

__device__ __forceinline__ unsigned short f2bf(float f) {
    union { float f; unsigned int u; } x; x.f = f;
    unsigned int u = x.u;
    unsigned int r = (u + 0x7fffu + ((u >> 16) & 1u)) >> 16;  // RNE
    return (unsigned short)r;
}
__device__ __forceinline__ float bf_lo(unsigned int v) { return __uint_as_float(v << 16); }
__device__ __forceinline__ float bf_hi(unsigned int v) { return __uint_as_float(v & 0xffff0000u); }

__device__ __forceinline__ void gll16(const void* g, void* l) {
    __builtin_amdgcn_global_load_lds(
        (const __attribute__((address_space(1))) unsigned int*)g,
        (__attribute__((address_space(3))) unsigned int*)l, 16, 0, 0);
}

template <int N> __device__ __forceinline__ void waitvm() {
    if constexpr (N == 0) asm volatile("s_waitcnt vmcnt(0)" ::: "memory");
    else if constexpr (N == 4) asm volatile("s_waitcnt vmcnt(4)" ::: "memory");
    else if constexpr (N == 6) asm volatile("s_waitcnt vmcnt(6)" ::: "memory");
    else static_assert(N == 0, "unhandled vmcnt");
}

__global__ void k_zero(int* p, int n) {
    int i = blockIdx.x * 256 + threadIdx.x;
    if (i < n) p[i] = 0;
}

// ---------------- fused: edge-scatter blocks + weight-transpose blocks ----------------

#define TPE 16

__device__ void scatter_body(int bid, const int* __restrict__ src,
                             const int* __restrict__ dst,
                             int* gcur, unsigned int* pairs, int E, int nbkt) {
    __shared__ int hist[512];
    __shared__ int base[512];
    const int tid = threadIdx.x;
    const int t0 = bid * (256 * TPE);
    if (t0 >= E) return;
    for (int i = tid; i < 512; i += 256) hist[i] = 0;
    __syncthreads();

    int es[TPE], ed[TPE], rk[TPE];
    bool valid[TPE];
    if (t0 + 256 * TPE <= E) {
        const int4* s4 = (const int4*)(src + t0 + tid * TPE);
        const int4* d4 = (const int4*)(dst + t0 + tid * TPE);
#pragma unroll
        for (int j = 0; j < TPE / 4; j++) {
            int4 a = s4[j], b = d4[j];
            es[4 * j + 0] = a.x; es[4 * j + 1] = a.y; es[4 * j + 2] = a.z; es[4 * j + 3] = a.w;
            ed[4 * j + 0] = b.x; ed[4 * j + 1] = b.y; ed[4 * j + 2] = b.z; ed[4 * j + 3] = b.w;
            valid[4 * j + 0] = valid[4 * j + 1] = valid[4 * j + 2] = valid[4 * j + 3] = true;
        }
    } else {
#pragma unroll
        for (int j = 0; j < TPE; j++) {
            int e = t0 + tid * TPE + j;
            valid[j] = (e < E);
            es[j] = valid[j] ? src[e] : 0;
            ed[j] = valid[j] ? dst[e] : 0;
        }
    }
#pragma unroll
    for (int j = 0; j < TPE; j++)
        if (valid[j]) rk[j] = atomicAdd(&hist[ed[j] >> BSH], 1);
    __syncthreads();
    for (int i = tid; i < nbkt; i += 256) {
        int c = hist[i];
        base[i] = c ? atomicAdd(&gcur[i], c) : 0;
    }
    __syncthreads();
#pragma unroll
    for (int j = 0; j < TPE; j++) {
        if (valid[j]) {
            int b = ed[j] >> BSH;
            int pos = base[b] + rk[j];
            if (pos < BCAP) {
                unsigned int p = ((unsigned int)(ed[j] & (BNODES - 1)) << 24) | (unsigned int)es[j];
                pairs[(size_t)b * BCAP + pos] = p;
            }
        }
    }
}

__device__ void wt_body(int bid, const float* __restrict__ W1, unsigned short* w1t,
                        const float* __restrict__ W2, unsigned short* w2t) {
    int i = bid * 256 + threadIdx.x;
    if (i < 1024 * 128) {
        int k = i >> 7, c = i & 127;
        w1t[c * 1024 + k] = f2bf(W1[i]);
    } else {
        int j = i - 1024 * 128;
        if (j < 128 * 128) {
            int k = j >> 7, c = j & 127;
            w2t[c * 128 + k] = f2bf(W2[j]);
        }
    }
}

__global__ __launch_bounds__(256) void k_prep(const int* __restrict__ src,
                                              const int* __restrict__ dst,
                                              int* gcur, unsigned int* pairs,
                                              int E, int nbkt, int SB,
                                              const float* __restrict__ W1, unsigned short* w1t,
                                              const float* __restrict__ W2, unsigned short* w2t) {
    if ((int)blockIdx.x < SB)
        scatter_body(blockIdx.x, src, dst, gcur, pairs, E, nbkt);
    else
        wt_body(blockIdx.x - SB, W1, w1t, W2, w2t);
}

// per-bucket grouping in the slab; emits offs/cnt/dinv pointing into padded csr
__global__ __launch_bounds__(512) void kB_group(const unsigned int* __restrict__ pairs,
                                                const int* __restrict__ gcur,
                                                int* csr, int* offs, int* cnt, float* dinv,
                                                int N, int nbkt) {
    int b = blockIdx.x;
    int p0 = b * BCAP;
    int psz = min(gcur[b], BCAP);
    int node0 = b << BSH;
    int nn = min(BNODES, N - node0);
    __shared__ int lcnt[BNODES];
    __shared__ int ss[BNODES];
    __shared__ int lcur[BNODES];
    int t = threadIdx.x;
    if (t < BNODES) lcnt[t] = 0;
    __syncthreads();
    for (int i = t; i < psz; i += 512)
        atomicAdd(&lcnt[pairs[p0 + i] >> 24], 1);
    __syncthreads();
    int v = (t < BNODES) ? lcnt[t] : 0;
    if (t < BNODES) ss[t] = v;
    __syncthreads();
    for (int o = 1; o < BNODES; o <<= 1) {
        int x = (t >= o && t < BNODES) ? ss[t - o] : 0;
        __syncthreads();
        if (t < BNODES) ss[t] += x;
        __syncthreads();
    }
    if (t < nn) {
        int o = p0 + ss[t] - v;
        offs[node0 + t] = o;
        cnt[node0 + t] = v;
        dinv[node0 + t] = rsqrtf((float)(v + 1));
        lcur[t] = o;
    }
    __syncthreads();
    for (int i = t; i < psz; i += 512) {
        unsigned int p = pairs[p0 + i];
        int pos = atomicAdd(&lcur[p >> 24], 1);
        csr[pos] = (int)(p & 0xFFFFFFu);
    }
}

// ---------------- GEMM (M x K) @ (K x 128) -> g = (XW)*dinv, bf16 ----------------
// 3-buffer counted-vmcnt pipeline + source-side LDS slot swizzle (round-10).

template <int K, bool IN_F32>
__global__ __launch_bounds__(256) void k_gemm(const void* __restrict__ Xv,
                                              const unsigned short* __restrict__ Wt,
                                              const float* __restrict__ dinv,
                                              unsigned short* __restrict__ G, int M) {
    constexpr int ABYTES = IN_F32 ? 128 * 32 * 4 : 128 * 32 * 2;
    constexpr int BBYTES = 128 * 32 * 2;
    constexpr int NT = K / 32;
    constexpr int NBUF = 3;
    constexpr int L = IN_F32 ? 6 : 4;
    static_assert(NT >= 3, "pipeline needs >=3 tiles");
    __shared__ char smem[NBUF * (ABYTES + BBYTES)];

    const int tid = threadIdx.x;
    const int m0 = blockIdx.x * 128;
    const int w = tid >> 6, l = tid & 63, r = l & 15, kg = l >> 4;
    const int wb0 = tid & ~63;

    auto stage = [&](int buf, int k0) {
        if (IN_F32) {
            const float* X = (const float*)Xv;
            char* ab = smem + buf * ABYTES;
#pragma unroll
            for (int i = 0; i < 4; i++) {
                int wb = i * 256 + wb0;
                int c = wb + l;
                int row = c >> 3, slot = c & 7;
                int g = (slot - (row & 7)) & 7;
                int srow = m0 + row; if (srow >= M) srow = M - 1;
                gll16(X + (size_t)srow * K + k0 + g * 4, ab + (size_t)wb * 16);
            }
        } else {
            const unsigned short* X = (const unsigned short*)Xv;
            char* ab = smem + buf * ABYTES;
#pragma unroll
            for (int i = 0; i < 2; i++) {
                int wb = i * 256 + wb0;
                int c = wb + l;
                int row = c >> 2, slot = c & 3;
                int g = (slot - (row >> 2)) & 3;
                int srow = m0 + row; if (srow >= M) srow = M - 1;
                gll16(X + (size_t)srow * K + k0 + g * 8, ab + (size_t)wb * 16);
            }
        }
        {
            char* bb = smem + NBUF * ABYTES + buf * BBYTES;
#pragma unroll
            for (int i = 0; i < 2; i++) {
                int wb = i * 256 + wb0;
                int c = wb + l;
                int row = c >> 2, slot = c & 3;
                int g = (slot - (row >> 2)) & 3;
                gll16(Wt + (size_t)row * K + k0 + g * 8, bb + (size_t)wb * 16);
            }
        }
    };

    f32x4 acc[2][8];
#pragma unroll
    for (int mt = 0; mt < 2; mt++)
#pragma unroll
        for (int ct = 0; ct < 8; ct++) acc[mt][ct] = (f32x4){0.f, 0.f, 0.f, 0.f};

    auto compute = [&](int buf) {
        bf16x8 af[2], bfr[8];
        if (IN_F32) {
            const float* ab = (const float*)(smem + buf * ABYTES);
#pragma unroll
            for (int mt = 0; mt < 2; mt++) {
                int row = w * 32 + mt * 16 + r;
                int p = row & 7;
                int s0 = (2 * kg + p) & 7, s1 = (2 * kg + 1 + p) & 7;
                float4 f0 = *(const float4*)(ab + row * 32 + s0 * 4);
                float4 f1 = *(const float4*)(ab + row * 32 + s1 * 4);
                union { bf16x8 v; unsigned short u[8]; } a;
                a.u[0] = f2bf(f0.x); a.u[1] = f2bf(f0.y); a.u[2] = f2bf(f0.z); a.u[3] = f2bf(f0.w);
                a.u[4] = f2bf(f1.x); a.u[5] = f2bf(f1.y); a.u[6] = f2bf(f1.z); a.u[7] = f2bf(f1.w);
                af[mt] = a.v;
            }
        } else {
            const unsigned short* ab = (const unsigned short*)(smem + buf * ABYTES);
#pragma unroll
            for (int mt = 0; mt < 2; mt++) {
                int row = w * 32 + mt * 16 + r;
                int s = (kg + (row >> 2)) & 3;
                af[mt] = *(const bf16x8*)(ab + row * 32 + s * 8);
            }
        }
        {
            const unsigned short* bb = (const unsigned short*)(smem + NBUF * ABYTES + buf * BBYTES);
#pragma unroll
            for (int ct = 0; ct < 8; ct++) {
                int rowb = ct * 16 + r;
                int s = (kg + (rowb >> 2)) & 3;
                bfr[ct] = *(const bf16x8*)(bb + rowb * 32 + s * 8);
            }
        }
#pragma unroll
        for (int mt = 0; mt < 2; mt++)
#pragma unroll
            for (int ct = 0; ct < 8; ct++)
                acc[mt][ct] = __builtin_amdgcn_mfma_f32_16x16x32_bf16(af[mt], bfr[ct], acc[mt][ct], 0, 0, 0);
    };

    stage(0, 0);
    stage(1, 32);

    int cur = 0;
    for (int t = 0; t < NT - 2; ++t) {
        int nb = cur + 2; if (nb >= NBUF) nb -= NBUF;
        waitvm<L>();
        __builtin_amdgcn_s_barrier();
        stage(nb, (t + 2) * 32);
        compute(cur);
        cur = (cur + 1 == NBUF) ? 0 : cur + 1;
    }
    waitvm<L>();
    __builtin_amdgcn_s_barrier();
    compute(cur);
    cur = (cur + 1 == NBUF) ? 0 : cur + 1;
    waitvm<0>();
    __builtin_amdgcn_s_barrier();
    compute(cur);

    // epilogue: C/D layout col = lane&15, row = 4*(lane>>4) + reg  [m89-verified]
#pragma unroll
    for (int mt = 0; mt < 2; mt++) {
        int rbase = m0 + w * 32 + mt * 16 + kg * 4;
        float dv[4];
#pragma unroll
        for (int q = 0; q < 4; q++) dv[q] = (rbase + q < M) ? dinv[rbase + q] : 0.f;
#pragma unroll
        for (int ct = 0; ct < 8; ct++) {
#pragma unroll
            for (int q = 0; q < 4; q++) {
                int gr = rbase + q;
                if (gr < M) G[(size_t)gr * 128 + ct * 16 + r] = f2bf(acc[mt][ct][q] * dv[q]);
            }
        }
    }
}

// ---------------- GEMM3: [M][128]bf16 @ [128][9]f32 -> g3 [M][16]bf16 (padded) ----------------

__global__ __launch_bounds__(256) void k_gemm3(const unsigned short* X3, const float* W3,
                                               const float* dinv, unsigned short* G3, int M) {
    __shared__ unsigned short sx[128 * 136];
    __shared__ float sw[128 * 9];
    int tid = threadIdx.x;
    int m0 = blockIdx.x * 128;
#pragma unroll
    for (int p = 0; p < 8; p++) {
        int idx = p * 256 + tid;
        int row = idx >> 4, c8 = idx & 15;
        uint4 v = make_uint4(0u, 0u, 0u, 0u);
        if (m0 + row < M) v = *(const uint4*)(X3 + (size_t)(m0 + row) * 128 + c8 * 8);
        *(uint4*)&sx[row * 136 + c8 * 8] = v;
    }
    for (int i = tid; i < 128 * 9; i += 256) sw[i] = W3[i];
    __syncthreads();

    int r = tid >> 1, h = tid & 1;
    float acc[9];
#pragma unroll
    for (int c = 0; c < 9; c++) acc[c] = 0.f;
    for (int kk = 0; kk < 64; kk++) {
        int k = h * 64 + kk;
        float xv = __uint_as_float(((unsigned int)sx[r * 136 + k]) << 16);
#pragma unroll
        for (int c = 0; c < 9; c++) acc[c] += xv * sw[k * 9 + c];
    }
#pragma unroll
    for (int c = 0; c < 9; c++) acc[c] += __shfl_xor(acc[c], 1);
    int gr = m0 + r;
    if (h == 0 && gr < M) {
        float dv = dinv[gr];
#pragma unroll
        for (int c = 0; c < 9; c++) G3[(size_t)gr * 16 + c] = f2bf(acc[c] * dv);
#pragma unroll
        for (int c = 9; c < 16; c++) G3[(size_t)gr * 16 + c] = 0;
    }
}

// ---------------- aggregation, 128-dim: LDS-staged csr, 8-deep gather pipeline ----------------

#define A128_CAP 1024

__global__ __launch_bounds__(256) void k_agg128(const unsigned int* __restrict__ gv,
                                                const int* __restrict__ csr,
                                                const int* __restrict__ offs,
                                                const int* __restrict__ cnt,
                                                const float* __restrict__ dinv,
                                                const float* __restrict__ bias,
                                                unsigned int* xout, int N, int do_relu) {
    __shared__ int sidx[A128_CAP];
    const int tid = threadIdx.x;
    const int n0 = blockIdx.x * 4;
    const int nlast = min(n0 + 3, N - 1);
    const int base = offs[n0];
    const int tot = offs[nlast] + cnt[nlast] - base;
    const bool lds_ok = (tot <= A128_CAP);
    if (lds_ok)
        for (int i = tid; i < tot; i += 256) sidx[i] = csr[base + i];
    __syncthreads();

    const int node = n0 + (tid >> 6);
    if (node >= N) return;
    const int l = tid & 63;
    const int ne = cnt[node];
    const int st = offs[node] - base;

    unsigned int u = gv[node * 64 + l];
    float a0 = bf_lo(u), a1 = bf_hi(u);
    int e = 0;
    if (lds_ok) {
        for (; e + 8 <= ne; e += 8) {
            int s0 = sidx[st + e], s1 = sidx[st + e + 1];
            int s2 = sidx[st + e + 2], s3 = sidx[st + e + 3];
            int s4 = sidx[st + e + 4], s5 = sidx[st + e + 5];
            int s6 = sidx[st + e + 6], s7 = sidx[st + e + 7];
            unsigned int v0 = gv[s0 * 64 + l], v1 = gv[s1 * 64 + l];
            unsigned int v2 = gv[s2 * 64 + l], v3 = gv[s3 * 64 + l];
            unsigned int v4 = gv[s4 * 64 + l], v5 = gv[s5 * 64 + l];
            unsigned int v6 = gv[s6 * 64 + l], v7 = gv[s7 * 64 + l];
            a0 += bf_lo(v0); a1 += bf_hi(v0);
            a0 += bf_lo(v1); a1 += bf_hi(v1);
            a0 += bf_lo(v2); a1 += bf_hi(v2);
            a0 += bf_lo(v3); a1 += bf_hi(v3);
            a0 += bf_lo(v4); a1 += bf_hi(v4);
            a0 += bf_lo(v5); a1 += bf_hi(v5);
            a0 += bf_lo(v6); a1 += bf_hi(v6);
            a0 += bf_lo(v7); a1 += bf_hi(v7);
        }
        for (; e < ne; e++) {
            unsigned int v = gv[sidx[st + e] * 64 + l];
            a0 += bf_lo(v); a1 += bf_hi(v);
        }
    } else {
        const int gst = offs[node];
        for (; e < ne; e++) {
            unsigned int v = gv[csr[gst + e] * 64 + l];
            a0 += bf_lo(v); a1 += bf_hi(v);
        }
    }
    float dv = dinv[node];
    float o0 = fmaf(dv, a0, bias[2 * l]);
    float o1 = fmaf(dv, a1, bias[2 * l + 1]);
    if (do_relu) { o0 = fmaxf(o0, 0.f); o1 = fmaxf(o1, 0.f); }
    xout[node * 64 + l] = (unsigned int)f2bf(o0) | ((unsigned int)f2bf(o1) << 16);
}

// ---------------- aggregation, 9-dim + log_softmax: 8 lanes/node, 32 nodes/block ----------------

#define A9_CAP 3072

__global__ __launch_bounds__(256) void k_agg9(const unsigned int* __restrict__ g3v,
                                              const int* __restrict__ csr,
                                              const int* __restrict__ offs,
                                              const int* __restrict__ cnt,
                                              const float* __restrict__ dinv,
                                              const float* __restrict__ b3,
                                              float* out, int N) {
    __shared__ int sidx[A9_CAP];
    const int tid = threadIdx.x;
    const int n0 = blockIdx.x * 32;
    const int nlast = min(n0 + 31, N - 1);
    const int base = offs[n0];
    const int tot = offs[nlast] + cnt[nlast] - base;
    const bool lds_ok = (tot <= A9_CAP);
    if (lds_ok)
        for (int i = tid; i < tot; i += 256) sidx[i] = csr[base + i];
    __syncthreads();

    const int node = n0 + (tid >> 3);
    if (node >= N) return;
    const int jl = tid & 7;
    const int ne = cnt[node];

    unsigned int u = g3v[node * 8 + jl];
    float a0 = bf_lo(u), a1 = bf_hi(u);
    int e = 0;
    if (lds_ok) {
        const int st = offs[node] - base;
        for (; e + 4 <= ne; e += 4) {
            int s0 = sidx[st + e], s1 = sidx[st + e + 1];
            int s2 = sidx[st + e + 2], s3 = sidx[st + e + 3];
            unsigned int v0 = g3v[s0 * 8 + jl], v1 = g3v[s1 * 8 + jl];
            unsigned int v2 = g3v[s2 * 8 + jl], v3 = g3v[s3 * 8 + jl];
            a0 += bf_lo(v0); a1 += bf_hi(v0);
            a0 += bf_lo(v1); a1 += bf_hi(v1);
            a0 += bf_lo(v2); a1 += bf_hi(v2);
            a0 += bf_lo(v3); a1 += bf_hi(v3);
        }
        for (; e < ne; e++) {
            unsigned int v = g3v[sidx[st + e] * 8 + jl];
            a0 += bf_lo(v); a1 += bf_hi(v);
        }
    } else {
        const int gst = offs[node];
        for (; e < ne; e++) {
            unsigned int v = g3v[csr[gst + e] * 8 + jl];
            a0 += bf_lo(v); a1 += bf_hi(v);
        }
    }
    float dv = dinv[node];
    int c0 = 2 * jl, c1 = 2 * jl + 1;
    float o0 = (c0 < 9) ? fmaf(dv, a0, b3[c0]) : -INFINITY;
    float o1 = (c1 < 9) ? fmaf(dv, a1, b3[c1]) : -INFINITY;
    float m = fmaxf(o0, o1);
    for (int d = 1; d < 8; d <<= 1) m = fmaxf(m, __shfl_xor(m, d));
    float s = 0.f;
    if (c0 < 9) s += expf(o0 - m);
    if (c1 < 9) s += expf(o1 - m);
    for (int d = 1; d < 8; d <<= 1) s += __shfl_xor(s, d);
    float ls = m + logf(s);
    if (c0 < 9) out[(size_t)node * 9 + c0] = o0 - ls;
    if (c1 < 9) out[(size_t)node * 9 + c1] = o1 - ls;
}

// ---------------- launch ----------------

extern "C" void kernel_launch(void* const* d_in, const int* in_sizes, int n_in,
                              void* d_out, int out_size, void* d_ws, size_t ws_size,
                              hipStream_t stream) {
    const float* x = (const float*)d_in[0];
    const int* ei = (const int*)d_in[1];
    const float* W1 = (const float*)d_in[2];
    const float* b1 = (const float*)d_in[3];
    const float* W2 = (const float*)d_in[4];
    const float* b2 = (const float*)d_in[5];
    const float* W3 = (const float*)d_in[6];
    const float* b3 = (const float*)d_in[7];
    float* out = (float*)d_out;

    const int N = in_sizes[0] / 1024;
    const int E = in_sizes[1] / 2;
    const int* src = ei;
    const int* dst = ei + E;
    const int nbkt = (N + BNODES - 1) >> BSH;

    char* ws = (char*)d_ws;
    size_t off = 0;
    auto alloc = [&](size_t bytes) -> char* {
        char* p = ws + off;
        off += (bytes + 255) & ~(size_t)255;
        return p;
    };
    int* cnt = (int*)alloc((size_t)N * 4);
    int* offs = (int*)alloc((size_t)N * 4);
    float* dinv = (float*)alloc((size_t)N * 4);
    int* gcur = (int*)alloc(520 * 4);
    unsigned int* pairs = (unsigned int*)alloc((size_t)nbkt * BCAP * 4);
    int* csr = (int*)alloc((size_t)nbkt * BCAP * 4);
    unsigned short* w1t = (unsigned short*)alloc(128 * 1024 * 2);
    unsigned short* w2t = (unsigned short*)alloc(128 * 128 * 2);
    unsigned short* gbuf = (unsigned short*)alloc((size_t)N * 128 * 2);
    unsigned short* xbuf = (unsigned short*)alloc((size_t)N * 128 * 2);
    unsigned short* g3 = (unsigned short*)alloc((size_t)N * 16 * 2);

    const int MB = (N + 127) / 128;
    const int AB = (N + 3) / 4;
    const int AB9 = (N + 31) / 32;
    const int SB = (E + 256 * TPE - 1) / (256 * TPE);
    const int WB = (1024 * 128 + 128 * 128 + 255) / 256;

    k_zero<<<3, 256, 0, stream>>>(gcur, 520);
    k_prep<<<SB + WB, 256, 0, stream>>>(src, dst, gcur, pairs, E, nbkt, SB, W1, w1t, W2, w2t);
    kB_group<<<nbkt, 512, 0, stream>>>(pairs, gcur, csr, offs, cnt, dinv, N, nbkt);

    k_gemm<1024, true><<<MB, 256, 0, stream>>>((const void*)x, w1t, dinv, gbuf, N);
    k_agg128<<<AB, 256, 0, stream>>>((const unsigned int*)gbuf, csr, offs, cnt, dinv, b1,
                                     (unsigned int*)xbuf, N, 1);
    k_gemm<128, false><<<MB, 256, 0, stream>>>((const void*)xbuf, w2t, dinv, gbuf, N);
    k_agg128<<<AB, 256, 0, stream>>>((const unsigned int*)gbuf, csr, offs, cnt, dinv, b2,
                                     (unsigned int*)xbuf, N, 1);
    k_gemm3<<<MB, 256, 0, stream>>>(xbuf, W3, dinv, g3, N);
    k_agg9<<<AB9, 256, 0, stream>>>((const unsigned int*)g3, csr, offs, cnt, dinv, b3, out, N);
}